// Round 3
// baseline (872.913 us; speedup 1.0000x reference)
//
#include <hip/hip_runtime.h>

#define IN_F 256
#define OUT_F 128
#define QKV_F 384   // fused q|k|v columns
#define HEADS 8
#define DKH 16

// ---------------------------------------------------------------------------
// Weight folding: W_all[256][384] = [Wq | Wk@Wattn | Wv@Wmsg]
// (associativity: (h@Wk+bk)@Wattn+battn == h@(Wk@Wattn) + (bk@Wattn+battn))
// ---------------------------------------------------------------------------
__global__ void prep_W(const float* __restrict__ Wq,
                       const float* __restrict__ Wk, const float* __restrict__ Wattn,
                       const float* __restrict__ Wv, const float* __restrict__ Wmsg,
                       float* __restrict__ W_all) {
    int k = blockIdx.x;      // 0..255
    int c = threadIdx.x;     // 0..383
    float r;
    if (c < 128) {
        r = Wq[k * 128 + c];
    } else if (c < 256) {
        int cc = c - 128;
        float s = 0.f;
        for (int j = 0; j < 128; ++j) s += Wk[k * 128 + j] * Wattn[j * 128 + cc];
        r = s;
    } else {
        int cc = c - 256;
        float s = 0.f;
        for (int j = 0; j < 128; ++j) s += Wv[k * 128 + j] * Wmsg[j * 128 + cc];
        r = s;
    }
    W_all[k * QKV_F + c] = r;
}

__global__ void prep_b(const float* __restrict__ bq, const float* __restrict__ bk,
                       const float* __restrict__ battn, const float* __restrict__ bv,
                       const float* __restrict__ bmsg, const float* __restrict__ Wattn,
                       const float* __restrict__ Wmsg, float* __restrict__ b_all) {
    int c = threadIdx.x;     // 0..383
    float r;
    if (c < 128) {
        r = bq[c];
    } else if (c < 256) {
        int cc = c - 128;
        float s = battn[cc];
        for (int j = 0; j < 128; ++j) s += bk[j] * Wattn[j * 128 + cc];
        r = s;
    } else {
        int cc = c - 256;
        float s = bmsg[cc];
        for (int j = 0; j < 128; ++j) s += bv[j] * Wmsg[j * 128 + cc];
        r = s;
    }
    b_all[c] = r;
}

// ---------------------------------------------------------------------------
// FP32 SGEMM with bias: C[M,N] = A[M,K] @ B[K,N] + bias[N]
// v2: 256 threads, BM=128 BN=128 BK=16, 8x8 per-thread microtile.
// Rows {tm..tm+3} U {64+tm..}, cols {tn..tn+3} U {64+tn..}: all four LDS
// fragment reads are b128 with only 2-way bank alias (free) or 16-way
// same-address broadcast (free). 64 FMA : 4 ds_read_b128 per kk.
// ---------------------------------------------------------------------------
#define BM 128
#define BN 128
#define BKS 16
__global__ __launch_bounds__(256) void sgemm_bias(
        const float* __restrict__ A, const float* __restrict__ B,
        const float* __restrict__ bias, float* __restrict__ C,
        int M, int N, int K) {
    __shared__ float As[BKS][BM];
    __shared__ float Bs[BKS][BN];
    int t  = threadIdx.x;
    int m0 = blockIdx.y * BM;
    int n0 = blockIdx.x * BN;
    int tm = (t & 15) * 4;   // row group
    int tn = (t >> 4) * 4;   // col group
    // staging assignments
    int ar  = t >> 1;          // A row 0..127
    int ak  = (t & 1) * 8;     // A k-half
    int bkr = t >> 4;          // B k row 0..15
    int bnc = (t & 15) * 8;    // B col (8 floats per thread)

    float acc[8][8];
#pragma unroll
    for (int i = 0; i < 8; ++i)
#pragma unroll
        for (int j = 0; j < 8; ++j) acc[i][j] = 0.f;

    const float* Ap = A + (size_t)(m0 + ar) * K + ak;
    bool aval = (m0 + ar) < M;
    const float* Bp = B + (size_t)bkr * N + n0 + bnc;

    for (int k0 = 0; k0 < K; k0 += BKS) {
        float4 a0 = make_float4(0.f, 0.f, 0.f, 0.f), a1 = a0;
        if (aval) {
            a0 = *(const float4*)(Ap + k0);
            a1 = *(const float4*)(Ap + k0 + 4);
        }
        float4 b0 = *(const float4*)(Bp + (size_t)k0 * N);
        float4 b1 = *(const float4*)(Bp + (size_t)k0 * N + 4);
        __syncthreads();   // previous iteration's LDS consumers done
        As[ak + 0][ar] = a0.x; As[ak + 1][ar] = a0.y;
        As[ak + 2][ar] = a0.z; As[ak + 3][ar] = a0.w;
        As[ak + 4][ar] = a1.x; As[ak + 5][ar] = a1.y;
        As[ak + 6][ar] = a1.z; As[ak + 7][ar] = a1.w;
        *(float4*)&Bs[bkr][bnc]     = b0;
        *(float4*)&Bs[bkr][bnc + 4] = b1;
        __syncthreads();
#pragma unroll
        for (int kk = 0; kk < BKS; ++kk) {
            float4 av0 = *(const float4*)&As[kk][tm];
            float4 av1 = *(const float4*)&As[kk][64 + tm];
            float4 bv0 = *(const float4*)&Bs[kk][tn];
            float4 bv1 = *(const float4*)&Bs[kk][64 + tn];
            float aa[8] = {av0.x, av0.y, av0.z, av0.w, av1.x, av1.y, av1.z, av1.w};
            float bb[8] = {bv0.x, bv0.y, bv0.z, bv0.w, bv1.x, bv1.y, bv1.z, bv1.w};
#pragma unroll
            for (int i = 0; i < 8; ++i)
#pragma unroll
                for (int j = 0; j < 8; ++j) acc[i][j] += aa[i] * bb[j];
        }
    }

    float4 bz0 = *(const float4*)(bias + n0 + tn);
    float4 bz1 = *(const float4*)(bias + n0 + 64 + tn);
    float bb0[8] = {bz0.x, bz0.y, bz0.z, bz0.w, bz1.x, bz1.y, bz1.z, bz1.w};
#pragma unroll
    for (int rh = 0; rh < 2; ++rh)
#pragma unroll
        for (int i = 0; i < 4; ++i) {
            int row = m0 + rh * 64 + tm + i;
            if (row < M) {
                int ai = rh * 4 + i;
#pragma unroll
                for (int ch = 0; ch < 2; ++ch) {
                    float4 o = make_float4(acc[ai][ch * 4 + 0] + bb0[ch * 4 + 0],
                                           acc[ai][ch * 4 + 1] + bb0[ch * 4 + 1],
                                           acc[ai][ch * 4 + 2] + bb0[ch * 4 + 2],
                                           acc[ai][ch * 4 + 3] + bb0[ch * 4 + 3]);
                    *(float4*)(C + (size_t)row * N + n0 + ch * 64 + tn) = o;
                }
            }
        }
}

// ---------------------------------------------------------------------------
// Counting sort of edges by dst: histogram -> 2-level exclusive scan -> scatter
// ---------------------------------------------------------------------------
__global__ void k_hist(const int* __restrict__ dst, int* __restrict__ deg, int e) {
    int i = blockIdx.x * 256 + threadIdx.x;
    if (i < e) atomicAdd(&deg[dst[i]], 1);
}

__global__ void k_scan1(const int* __restrict__ in, int* __restrict__ out,
                        int* __restrict__ bsums, int n) {
    __shared__ int sc[256];
    int t = threadIdx.x;
    int base = blockIdx.x * 1024 + t * 4;
    int v[4];
#pragma unroll
    for (int i = 0; i < 4; ++i) v[i] = (base + i < n) ? in[base + i] : 0;
    int tsum = v[0] + v[1] + v[2] + v[3];
    sc[t] = tsum;
    __syncthreads();
    for (int off = 1; off < 256; off <<= 1) {
        int x = 0;
        if (t >= off) x = sc[t - off];
        __syncthreads();
        sc[t] += x;
        __syncthreads();
    }
    int incl = sc[t];
    int e = incl - tsum;    // exclusive prefix for this thread
#pragma unroll
    for (int i = 0; i < 4; ++i) {
        if (base + i < n) out[base + i] = e;
        e += v[i];
    }
    if (t == 255) bsums[blockIdx.x] = incl;
}

__global__ void k_scan2(int* __restrict__ bsums, int nb) {
    __shared__ int sc[256];
    int t = threadIdx.x;
    int v = (t < nb) ? bsums[t] : 0;
    sc[t] = v;
    __syncthreads();
    for (int off = 1; off < 256; off <<= 1) {
        int x = 0;
        if (t >= off) x = sc[t - off];
        __syncthreads();
        sc[t] += x;
        __syncthreads();
    }
    if (t < nb) bsums[t] = sc[t] - v;   // exclusive
}

__global__ void k_scan3(int* __restrict__ out, const int* __restrict__ bsums, int n) {
    int i = blockIdx.x * 256 + threadIdx.x;
    if (i < n) out[i] += bsums[blockIdx.x >> 2];   // 1024 elems per bsum chunk
}

__global__ void k_scatter(const int* __restrict__ src, const int* __restrict__ dst,
                          const int* __restrict__ row_start, int* __restrict__ cursor,
                          int* __restrict__ sorted_src, int e) {
    int i = blockIdx.x * 256 + threadIdx.x;
    if (i < e) {
        int d  = dst[i];
        int p  = atomicAdd(&cursor[d], 1);
        sorted_src[row_start[d] + p] = src[i];
    }
}

// ---------------------------------------------------------------------------
// Fused SDDMM + edge-softmax + SPMM. One wave per dst node.
// Chunked TWO-PASS softmax. Per <=64-edge chunk:
//   pass A: independent k-row gathers -> per-head dot (3x shfl_xor over the
//           8-lane head group) -> scores to LDS.  No inter-edge dependency.
//   mid:    parallel chunk max / exp / denominator (8 exps per lane), ONE
//           rescale per chunk.
//   pass B: independent v-row gathers, 2 FMAs per edge per lane.
// Lane l owns feature dims {2l,2l+1}; head = l>>3.
// LDS scores [8][65] per wave: 65-pad => scan reads are a bijection mod 32
// banks (2-way alias, free); pass-B reads are 8-address broadcasts.
// ---------------------------------------------------------------------------
__global__ __launch_bounds__(256) void edge_agg(
        const float* __restrict__ qkv, const int* __restrict__ row_start,
        const int* __restrict__ deg, const int* __restrict__ sorted_src,
        float* __restrict__ agg, int nnodes) {
    __shared__ float sS[4][8][65];
    int wid  = threadIdx.x >> 6;
    int lane = threadIdx.x & 63;
    int node = blockIdx.x * 4 + wid;
    if (node >= nnodes) return;
    int h  = lane >> 3;        // this lane's head
    int j0 = (lane & 7) * 8;   // score slots this lane owns in scan phases
    float* srow = &sS[wid][h][0];

    const float2 qv = *(const float2*)(qkv + (size_t)node * QKV_F + 2 * lane);
    float m = -INFINITY, z = 0.f, acc0 = 0.f, acc1 = 0.f;
    int rs = row_start[node];
    int dg = deg[node];

    for (int base = 0; base < dg; base += 64) {
        int nb = min(64, dg - base);
        int my_src = (base + lane < dg) ? sorted_src[rs + base + lane] : 0;

        // ---- pass A: scores -> LDS (loads independent across j) ----
#pragma unroll 4
        for (int j = 0; j < nb; ++j) {
            int sn = __shfl(my_src, j);
            float2 kv = *(const float2*)(qkv + (size_t)sn * QKV_F + 128 + 2 * lane);
            float p = kv.x * qv.x + kv.y * qv.y;
            p += __shfl_xor(p, 1);
            p += __shfl_xor(p, 2);
            p += __shfl_xor(p, 4);
            if ((lane & 7) == 0) srow[j] = p * 0.25f;   // 1/sqrt(16)
        }

        // ---- chunk softmax: max, exp, denom — all parallel ----
        float sv[8];
        float cm = -INFINITY;
#pragma unroll
        for (int i = 0; i < 8; ++i) {
            sv[i] = (j0 + i < nb) ? srow[j0 + i] : -INFINITY;
            cm = fmaxf(cm, sv[i]);
        }
        cm = fmaxf(cm, __shfl_xor(cm, 1));
        cm = fmaxf(cm, __shfl_xor(cm, 2));
        cm = fmaxf(cm, __shfl_xor(cm, 4));
        float mn = fmaxf(m, cm);        // nb>=1 => cm finite => mn finite
        float zc = 0.f;
#pragma unroll
        for (int i = 0; i < 8; ++i) {
            float p = __expf(sv[i] - mn);   // padded slots: exp(-inf)=0
            srow[j0 + i] = p;               // overwrite score with weight
            zc += p;
        }
        zc += __shfl_xor(zc, 1);
        zc += __shfl_xor(zc, 2);
        zc += __shfl_xor(zc, 4);
        float f = __expf(m - mn);           // first chunk: exp(-inf)=0, z=0 ok
        z = z * f + zc;
        acc0 *= f; acc1 *= f;
        m = mn;

        // ---- pass B: weighted V accumulate (loads independent across j) ----
#pragma unroll 4
        for (int j = 0; j < nb; ++j) {
            int sn = __shfl(my_src, j);
            float2 vv = *(const float2*)(qkv + (size_t)sn * QKV_F + 256 + 2 * lane);
            float w = srow[j];              // broadcast read
            acc0 += w * vv.x;
            acc1 += w * vv.y;
        }
    }
    float inv = (z > 0.f) ? 1.f / z : 0.f;   // deg-0 node -> zeros (ref: segsum=0)
    *(float2*)(agg + (size_t)node * OUT_F + 2 * lane) =
        make_float2(acc0 * inv, acc1 * inv);
}

// ---------------------------------------------------------------------------
extern "C" void kernel_launch(void* const* d_in, const int* in_sizes, int n_in,
                              void* d_out, int out_size, void* d_ws, size_t ws_size,
                              hipStream_t stream) {
    const float* h     = (const float*)d_in[0];
    const float* Wq    = (const float*)d_in[1];
    const float* bq    = (const float*)d_in[2];
    const float* Wk    = (const float*)d_in[3];
    const float* bk    = (const float*)d_in[4];
    const float* Wv    = (const float*)d_in[5];
    const float* bv    = (const float*)d_in[6];
    const float* Wmsg  = (const float*)d_in[7];
    const float* bmsg  = (const float*)d_in[8];
    const float* Wattn = (const float*)d_in[9];
    const float* battn = (const float*)d_in[10];
    const float* Wa    = (const float*)d_in[11];
    const float* ba    = (const float*)d_in[12];
    const int*   src   = (const int*)d_in[13];
    const int*   dst   = (const int*)d_in[14];
    float* out = (float*)d_out;

    int nn = in_sizes[0] / IN_F;   // 100000
    int ne = in_sizes[13];         // 1600000

    char* p = (char*)d_ws;
    auto carve = [&](size_t bytes) {
        char* r = p;
        p += (bytes + 255) & ~(size_t)255;
        return r;
    };
    float* W_all = (float*)carve((size_t)IN_F * QKV_F * 4);
    float* b_all = (float*)carve((size_t)QKV_F * 4);
    float* qkv   = (float*)carve((size_t)nn * QKV_F * 4);
    float* agg   = (float*)carve((size_t)nn * OUT_F * 4);
    int* deg     = (int*)carve((size_t)nn * 4);
    int* rowst   = (int*)carve((size_t)nn * 4);
    int* cursor  = (int*)carve((size_t)nn * 4);
    int* bsums   = (int*)carve(4096);
    int* ssrc    = (int*)carve((size_t)ne * 4);

    hipMemsetAsync(deg, 0, (size_t)nn * 4, stream);
    hipMemsetAsync(cursor, 0, (size_t)nn * 4, stream);

    prep_W<<<IN_F, QKV_F, 0, stream>>>(Wq, Wk, Wattn, Wv, Wmsg, W_all);
    prep_b<<<1, QKV_F, 0, stream>>>(bq, bk, battn, bv, bmsg, Wattn, Wmsg, b_all);

    // qkv[N,384] = h @ W_all + b_all
    sgemm_bias<<<dim3(QKV_F / BN, (nn + BM - 1) / BM), 256, 0, stream>>>(
        h, W_all, b_all, qkv, nn, QKV_F, IN_F);

    // counting sort edges by dst
    k_hist<<<(ne + 255) / 256, 256, 0, stream>>>(dst, deg, ne);
    int nb = (nn + 1023) / 1024;
    k_scan1<<<nb, 256, 0, stream>>>(deg, rowst, bsums, nn);
    k_scan2<<<1, 256, 0, stream>>>(bsums, nb);
    k_scan3<<<(nn + 255) / 256, 256, 0, stream>>>(rowst, bsums, nn);
    k_scatter<<<(ne + 255) / 256, 256, 0, stream>>>(src, dst, rowst, cursor, ssrc, ne);

    // fused SDDMM + softmax + SPMM
    edge_agg<<<(nn + 3) / 4, 256, 0, stream>>>(qkv, rowst, deg, ssrc, agg, nn);

    // out = agg @ Wa + ba
    sgemm_bias<<<dim3(OUT_F / BN, (nn + BM - 1) / BM), 256, 0, stream>>>(
        agg, Wa, ba, out, nn, OUT_F, OUT_F);
}

// Round 5
// 829.032 us; speedup vs baseline: 1.0529x; 1.0529x over previous
//
#include <hip/hip_runtime.h>
#include <hip/hip_fp16.h>

#define IN_F 256
#define OUT_F 128
#define QKV_F 384   // fused q|k|v columns
#define HEADS 8
#define DKH 16

// ---------------------------------------------------------------------------
// Weight folding: W_all[256][384] = [Wq | Wk@Wattn | Wv@Wmsg]
// ---------------------------------------------------------------------------
__global__ void prep_W(const float* __restrict__ Wq,
                       const float* __restrict__ Wk, const float* __restrict__ Wattn,
                       const float* __restrict__ Wv, const float* __restrict__ Wmsg,
                       float* __restrict__ W_all) {
    int k = blockIdx.x;      // 0..255
    int c = threadIdx.x;     // 0..383
    float r;
    if (c < 128) {
        r = Wq[k * 128 + c];
    } else if (c < 256) {
        int cc = c - 128;
        float s = 0.f;
        for (int j = 0; j < 128; ++j) s += Wk[k * 128 + j] * Wattn[j * 128 + cc];
        r = s;
    } else {
        int cc = c - 256;
        float s = 0.f;
        for (int j = 0; j < 128; ++j) s += Wv[k * 128 + j] * Wmsg[j * 128 + cc];
        r = s;
    }
    W_all[k * QKV_F + c] = r;
}

__global__ void prep_b(const float* __restrict__ bq, const float* __restrict__ bk,
                       const float* __restrict__ battn, const float* __restrict__ bv,
                       const float* __restrict__ bmsg, const float* __restrict__ Wattn,
                       const float* __restrict__ Wmsg, float* __restrict__ b_all) {
    int c = threadIdx.x;     // 0..383
    float r;
    if (c < 128) {
        r = bq[c];
    } else if (c < 256) {
        int cc = c - 128;
        float s = battn[cc];
        for (int j = 0; j < 128; ++j) s += bk[j] * Wattn[j * 128 + cc];
        r = s;
    } else {
        int cc = c - 256;
        float s = bmsg[cc];
        for (int j = 0; j < 128; ++j) s += bv[j] * Wmsg[j * 128 + cc];
        r = s;
    }
    b_all[c] = r;
}

// ---------------------------------------------------------------------------
// FP32 SGEMM with bias: 256 threads, BM=128 BN=128 BK=16, 8x8 microtile.
// Epilogue: if kv16 != nullptr, cols>=128 are stored ONLY as fp16 into
// kv16[row*256 + col-128] (k then v halves); cols<128 go fp32 to C (ldc).
// ---------------------------------------------------------------------------
#define BM 128
#define BN 128
#define BKS 16
__global__ __launch_bounds__(256) void sgemm_bias(
        const float* __restrict__ A, const float* __restrict__ B,
        const float* __restrict__ bias, float* __restrict__ C, int ldc,
        __half* __restrict__ kv16,
        int M, int N, int K) {
    __shared__ float As[BKS][BM];
    __shared__ float Bs[BKS][BN];
    int t  = threadIdx.x;
    int m0 = blockIdx.y * BM;
    int n0 = blockIdx.x * BN;
    int tm = (t & 15) * 4;   // row group
    int tn = (t >> 4) * 4;   // col group
    int ar  = t >> 1;          // A row 0..127
    int ak  = (t & 1) * 8;     // A k-half
    int bkr = t >> 4;          // B k row 0..15
    int bnc = (t & 15) * 8;    // B col (8 floats per thread)

    float acc[8][8];
#pragma unroll
    for (int i = 0; i < 8; ++i)
#pragma unroll
        for (int j = 0; j < 8; ++j) acc[i][j] = 0.f;

    const float* Ap = A + (size_t)(m0 + ar) * K + ak;
    bool aval = (m0 + ar) < M;
    const float* Bp = B + (size_t)bkr * N + n0 + bnc;

    for (int k0 = 0; k0 < K; k0 += BKS) {
        float4 a0 = make_float4(0.f, 0.f, 0.f, 0.f), a1 = a0;
        if (aval) {
            a0 = *(const float4*)(Ap + k0);
            a1 = *(const float4*)(Ap + k0 + 4);
        }
        float4 b0 = *(const float4*)(Bp + (size_t)k0 * N);
        float4 b1 = *(const float4*)(Bp + (size_t)k0 * N + 4);
        __syncthreads();
        As[ak + 0][ar] = a0.x; As[ak + 1][ar] = a0.y;
        As[ak + 2][ar] = a0.z; As[ak + 3][ar] = a0.w;
        As[ak + 4][ar] = a1.x; As[ak + 5][ar] = a1.y;
        As[ak + 6][ar] = a1.z; As[ak + 7][ar] = a1.w;
        *(float4*)&Bs[bkr][bnc]     = b0;
        *(float4*)&Bs[bkr][bnc + 4] = b1;
        __syncthreads();
#pragma unroll
        for (int kk = 0; kk < BKS; ++kk) {
            float4 av0 = *(const float4*)&As[kk][tm];
            float4 av1 = *(const float4*)&As[kk][64 + tm];
            float4 bv0 = *(const float4*)&Bs[kk][tn];
            float4 bv1 = *(const float4*)&Bs[kk][64 + tn];
            float aa[8] = {av0.x, av0.y, av0.z, av0.w, av1.x, av1.y, av1.z, av1.w};
            float bb[8] = {bv0.x, bv0.y, bv0.z, bv0.w, bv1.x, bv1.y, bv1.z, bv1.w};
#pragma unroll
            for (int i = 0; i < 8; ++i)
#pragma unroll
                for (int j = 0; j < 8; ++j) acc[i][j] += aa[i] * bb[j];
        }
    }

    float4 bz0 = *(const float4*)(bias + n0 + tn);
    float4 bz1 = *(const float4*)(bias + n0 + 64 + tn);
    float bb0[8] = {bz0.x, bz0.y, bz0.z, bz0.w, bz1.x, bz1.y, bz1.z, bz1.w};
#pragma unroll
    for (int rh = 0; rh < 2; ++rh)
#pragma unroll
        for (int i = 0; i < 4; ++i) {
            int row = m0 + rh * 64 + tm + i;
            if (row < M) {
                int ai = rh * 4 + i;
#pragma unroll
                for (int ch = 0; ch < 2; ++ch) {
                    float4 o = make_float4(acc[ai][ch * 4 + 0] + bb0[ch * 4 + 0],
                                           acc[ai][ch * 4 + 1] + bb0[ch * 4 + 1],
                                           acc[ai][ch * 4 + 2] + bb0[ch * 4 + 2],
                                           acc[ai][ch * 4 + 3] + bb0[ch * 4 + 3]);
                    int col0 = n0 + ch * 64 + tn;
                    if (kv16) {
                        if (col0 >= 128) {   // k|v -> fp16 only
                            __half2* dp = (__half2*)(kv16 + (size_t)row * 256 + (col0 - 128));
                            dp[0] = __floats2half2_rn(o.x, o.y);
                            dp[1] = __floats2half2_rn(o.z, o.w);
                        } else {             // q -> fp32, row stride ldc
                            *(float4*)(C + (size_t)row * ldc + col0) = o;
                        }
                    } else {
                        *(float4*)(C + (size_t)row * ldc + col0) = o;
                    }
                }
            }
        }
}

// ---------------------------------------------------------------------------
// Counting sort of edges by dst: histogram -> 2-level exclusive scan -> scatter
// ---------------------------------------------------------------------------
__global__ void k_hist(const int* __restrict__ dst, int* __restrict__ deg, int e) {
    int i = blockIdx.x * 256 + threadIdx.x;
    if (i < e) atomicAdd(&deg[dst[i]], 1);
}

__global__ void k_scan1(const int* __restrict__ in, int* __restrict__ out,
                        int* __restrict__ bsums, int n) {
    __shared__ int sc[256];
    int t = threadIdx.x;
    int base = blockIdx.x * 1024 + t * 4;
    int v[4];
#pragma unroll
    for (int i = 0; i < 4; ++i) v[i] = (base + i < n) ? in[base + i] : 0;
    int tsum = v[0] + v[1] + v[2] + v[3];
    sc[t] = tsum;
    __syncthreads();
    for (int off = 1; off < 256; off <<= 1) {
        int x = 0;
        if (t >= off) x = sc[t - off];
        __syncthreads();
        sc[t] += x;
        __syncthreads();
    }
    int incl = sc[t];
    int e = incl - tsum;
#pragma unroll
    for (int i = 0; i < 4; ++i) {
        if (base + i < n) out[base + i] = e;
        e += v[i];
    }
    if (t == 255) bsums[blockIdx.x] = incl;
}

__global__ void k_scan2(int* __restrict__ bsums, int nb) {
    __shared__ int sc[256];
    int t = threadIdx.x;
    int v = (t < nb) ? bsums[t] : 0;
    sc[t] = v;
    __syncthreads();
    for (int off = 1; off < 256; off <<= 1) {
        int x = 0;
        if (t >= off) x = sc[t - off];
        __syncthreads();
        sc[t] += x;
        __syncthreads();
    }
    if (t < nb) bsums[t] = sc[t] - v;
}

__global__ void k_scan3(int* __restrict__ out, const int* __restrict__ bsums, int n) {
    int i = blockIdx.x * 256 + threadIdx.x;
    if (i < n) out[i] += bsums[blockIdx.x >> 2];
}

__global__ void k_scatter(const int* __restrict__ src, const int* __restrict__ dst,
                          const int* __restrict__ row_start, int* __restrict__ cursor,
                          int* __restrict__ sorted_src, int e) {
    int i = blockIdx.x * 256 + threadIdx.x;
    if (i < e) {
        int d  = dst[i];
        int p  = atomicAdd(&cursor[d], 1);
        sorted_src[row_start[d] + p] = src[i];
    }
}

// ---------------------------------------------------------------------------
// Fused SDDMM + edge-softmax + SPMM. One wave per dst node; k/v gathered as
// fp16 (4B per lane per access -> 256B per row visit; 51.2MB footprint is
// L3-resident). Chunked two-pass softmax.
// ---------------------------------------------------------------------------
__global__ __launch_bounds__(256) void edge_agg(
        const float* __restrict__ qbuf, const __half* __restrict__ kv16,
        const int* __restrict__ row_start, const int* __restrict__ deg,
        const int* __restrict__ sorted_src,
        float* __restrict__ agg, int nnodes) {
    __shared__ float sS[4][8][65];
    int wid  = threadIdx.x >> 6;
    int lane = threadIdx.x & 63;
    int node = blockIdx.x * 4 + wid;
    if (node >= nnodes) return;
    int h  = lane >> 3;        // this lane's head
    int j0 = (lane & 7) * 8;   // score slots this lane owns in scan phases
    float* srow = &sS[wid][h][0];

    const float2 qv = *(const float2*)(qbuf + (size_t)node * 128 + 2 * lane);
    float m = -INFINITY, z = 0.f, acc0 = 0.f, acc1 = 0.f;
    int rs = row_start[node];
    int dg = deg[node];

    for (int base = 0; base < dg; base += 64) {
        int nb = min(64, dg - base);
        int my_src = (base + lane < dg) ? sorted_src[rs + base + lane] : 0;

        // ---- pass A: scores -> LDS ----
#pragma unroll 4
        for (int j = 0; j < nb; ++j) {
            int sn = __shfl(my_src, j);
            float2 kv = __half22float2(
                *(const __half2*)(kv16 + (size_t)sn * 256 + 2 * lane));
            float p = kv.x * qv.x + kv.y * qv.y;
            p += __shfl_xor(p, 1);
            p += __shfl_xor(p, 2);
            p += __shfl_xor(p, 4);
            if ((lane & 7) == 0) srow[j] = p * 0.25f;   // 1/sqrt(16)
        }

        // ---- chunk softmax: max, exp, denom — all parallel ----
        float sv[8];
        float cm = -INFINITY;
#pragma unroll
        for (int i = 0; i < 8; ++i) {
            sv[i] = (j0 + i < nb) ? srow[j0 + i] : -INFINITY;
            cm = fmaxf(cm, sv[i]);
        }
        cm = fmaxf(cm, __shfl_xor(cm, 1));
        cm = fmaxf(cm, __shfl_xor(cm, 2));
        cm = fmaxf(cm, __shfl_xor(cm, 4));
        float mn = fmaxf(m, cm);
        float zc = 0.f;
#pragma unroll
        for (int i = 0; i < 8; ++i) {
            float p = __expf(sv[i] - mn);   // padded slots: exp(-inf)=0
            srow[j0 + i] = p;
            zc += p;
        }
        zc += __shfl_xor(zc, 1);
        zc += __shfl_xor(zc, 2);
        zc += __shfl_xor(zc, 4);
        float f = __expf(m - mn);           // first chunk: exp(-inf)=0
        z = z * f + zc;
        acc0 *= f; acc1 *= f;
        m = mn;

        // ---- pass B: weighted V accumulate ----
#pragma unroll 4
        for (int j = 0; j < nb; ++j) {
            int sn = __shfl(my_src, j);
            float2 vv = __half22float2(
                *(const __half2*)(kv16 + (size_t)sn * 256 + 128 + 2 * lane));
            float w = srow[j];              // broadcast read
            acc0 += w * vv.x;
            acc1 += w * vv.y;
        }
    }
    float inv = (z > 0.f) ? 1.f / z : 0.f;   // deg-0 node -> zeros
    *(float2*)(agg + (size_t)node * OUT_F + 2 * lane) =
        make_float2(acc0 * inv, acc1 * inv);
}

// ---------------------------------------------------------------------------
extern "C" void kernel_launch(void* const* d_in, const int* in_sizes, int n_in,
                              void* d_out, int out_size, void* d_ws, size_t ws_size,
                              hipStream_t stream) {
    const float* h     = (const float*)d_in[0];
    const float* Wq    = (const float*)d_in[1];
    const float* bq    = (const float*)d_in[2];
    const float* Wk    = (const float*)d_in[3];
    const float* bk    = (const float*)d_in[4];
    const float* Wv    = (const float*)d_in[5];
    const float* bv    = (const float*)d_in[6];
    const float* Wmsg  = (const float*)d_in[7];
    const float* bmsg  = (const float*)d_in[8];
    const float* Wattn = (const float*)d_in[9];
    const float* battn = (const float*)d_in[10];
    const float* Wa    = (const float*)d_in[11];
    const float* ba    = (const float*)d_in[12];
    const int*   src   = (const int*)d_in[13];
    const int*   dst   = (const int*)d_in[14];
    float* out = (float*)d_out;

    int nn = in_sizes[0] / IN_F;   // 100000
    int ne = in_sizes[13];         // 1600000

    char* p = (char*)d_ws;
    auto carve = [&](size_t bytes) {
        char* r = p;
        p += (bytes + 255) & ~(size_t)255;
        return r;
    };
    float*  W_all = (float*)carve((size_t)IN_F * QKV_F * 4);
    float*  b_all = (float*)carve((size_t)QKV_F * 4);
    float*  qbuf  = (float*)carve((size_t)nn * 128 * 4);
    __half* kv16  = (__half*)carve((size_t)nn * 256 * 2);
    float*  agg   = (float*)carve((size_t)nn * OUT_F * 4);
    int* deg     = (int*)carve((size_t)nn * 4);
    int* rowst   = (int*)carve((size_t)nn * 4);
    int* cursor  = (int*)carve((size_t)nn * 4);
    int* bsums   = (int*)carve(4096);
    int* ssrc    = (int*)carve((size_t)ne * 4);

    hipMemsetAsync(deg, 0, (size_t)nn * 4, stream);
    hipMemsetAsync(cursor, 0, (size_t)nn * 4, stream);

    prep_W<<<IN_F, QKV_F, 0, stream>>>(Wq, Wk, Wattn, Wv, Wmsg, W_all);
    prep_b<<<1, QKV_F, 0, stream>>>(bq, bk, battn, bv, bmsg, Wattn, Wmsg, b_all);

    // q (fp32) + k|v (fp16) = h @ W_all + b_all
    sgemm_bias<<<dim3(QKV_F / BN, (nn + BM - 1) / BM), 256, 0, stream>>>(
        h, W_all, b_all, qbuf, 128, kv16, nn, QKV_F, IN_F);

    // counting sort edges by dst
    k_hist<<<(ne + 255) / 256, 256, 0, stream>>>(dst, deg, ne);
    int nb = (nn + 1023) / 1024;
    k_scan1<<<nb, 256, 0, stream>>>(deg, rowst, bsums, nn);
    k_scan2<<<1, 256, 0, stream>>>(bsums, nb);
    k_scan3<<<(nn + 255) / 256, 256, 0, stream>>>(rowst, bsums, nn);
    k_scatter<<<(ne + 255) / 256, 256, 0, stream>>>(src, dst, rowst, cursor, ssrc, ne);

    // fused SDDMM + softmax + SPMM
    edge_agg<<<(nn + 3) / 4, 256, 0, stream>>>(qbuf, kv16, rowst, deg, ssrc, agg, nn);

    // out = agg @ Wa + ba
    sgemm_bias<<<dim3(OUT_F / BN, (nn + BM - 1) / BM), 256, 0, stream>>>(
        agg, Wa, ba, out, OUT_F, nullptr, nn, OUT_F, OUT_F);
}

// Round 6
// 713.365 us; speedup vs baseline: 1.2237x; 1.1621x over previous
//
#include <hip/hip_runtime.h>
#include <hip/hip_fp16.h>

#define IN_F 256
#define OUT_F 128
#define QKV_F 384   // fused q|k|v columns
#define HEADS 8
#define DKH 16

typedef _Float16 f16x8 __attribute__((ext_vector_type(8)));
typedef float    f32x4 __attribute__((ext_vector_type(4)));

// ---------------------------------------------------------------------------
// Weight folding: WT_all[384][256] (fp16, TRANSPOSED) = [Wq | Wk@Wattn | Wv@Wmsg]^T
// ---------------------------------------------------------------------------
__global__ void prep_W(const float* __restrict__ Wq,
                       const float* __restrict__ Wk, const float* __restrict__ Wattn,
                       const float* __restrict__ Wv, const float* __restrict__ Wmsg,
                       _Float16* __restrict__ WT_all) {
    int k = blockIdx.x;      // 0..255 (input dim)
    int c = threadIdx.x;     // 0..383 (output col)
    float r;
    if (c < 128) {
        r = Wq[k * 128 + c];
    } else if (c < 256) {
        int cc = c - 128;
        float s = 0.f;
        for (int j = 0; j < 128; ++j) s += Wk[k * 128 + j] * Wattn[j * 128 + cc];
        r = s;
    } else {
        int cc = c - 256;
        float s = 0.f;
        for (int j = 0; j < 128; ++j) s += Wv[k * 128 + j] * Wmsg[j * 128 + cc];
        r = s;
    }
    WT_all[(size_t)c * IN_F + k] = (_Float16)r;   // transposed store
}

__global__ void prep_b(const float* __restrict__ bq, const float* __restrict__ bk,
                       const float* __restrict__ battn, const float* __restrict__ bv,
                       const float* __restrict__ bmsg, const float* __restrict__ Wattn,
                       const float* __restrict__ Wmsg, float* __restrict__ b_all) {
    int c = threadIdx.x;     // 0..383
    float r;
    if (c < 128) {
        r = bq[c];
    } else if (c < 256) {
        int cc = c - 128;
        float s = battn[cc];
        for (int j = 0; j < 128; ++j) s += bk[j] * Wattn[j * 128 + cc];
        r = s;
    } else {
        int cc = c - 256;
        float s = bmsg[cc];
        for (int j = 0; j < 128; ++j) s += bv[j] * Wmsg[j * 128 + cc];
        r = s;
    }
    b_all[c] = r;
}

// transpose + cast fp32 W[K][N] -> fp16 WT[N][K]
__global__ void t_cast16(const float* __restrict__ W, _Float16* __restrict__ WT,
                         int K, int N) {
    int k = blockIdx.x;
    int c = threadIdx.x;
    WT[(size_t)c * K + k] = (_Float16)W[(size_t)k * N + c];
}

// ---------------------------------------------------------------------------
// fp16-MFMA GEMM: C[M,ND] = A[M,KD](fp32, cast on stage) @ BT[ND,KD](fp16) + bias
// Block: 256 thr (4 waves), BM=64 rows. Wave w owns cols [w*ND/4, (w+1)*ND/4).
// Per wave: 4 m-tiles x (ND/64) n-tiles of 16x16, K-loop in steps of 32.
// A staged in LDS fp16 with 16B-granule XOR swizzle (k ^= 8*(r&7)) ->
// fragment ds_read_b128 conflict-free (r, r+8 share a bank slot: 2-way, free).
// B fragments: direct global 16B loads from BT (L2-resident weights).
// QKV epilogue: col<128 -> q fp32 [M][128]; col>=128 -> kv fp16 [M][256].
// ---------------------------------------------------------------------------
template<int KD, int ND, bool QKV_EPI>
__global__ __launch_bounds__(256) void mfma_gemm(
        const float* __restrict__ A, const _Float16* __restrict__ BT,
        const float* __restrict__ bias, float* __restrict__ Cq,
        __half* __restrict__ kv16, int M) {
    constexpr int BMR  = 64;
    constexpr int NT_W = ND / 64;          // n-tiles per wave (6 for 384, 2 for 128)
    __shared__ __align__(16) _Float16 As[BMR * KD];

    int t   = threadIdx.x;
    int wv  = t >> 6;
    int L   = t & 63;
    int row0 = blockIdx.x * BMR;

    // ---- stage A tile: fp32 -> fp16, swizzled. 4 threads per row. ----
    {
        int r   = t >> 2;
        int sub = t & 3;
        int gr  = row0 + r;
        const float* Ap = A + (size_t)gr * KD;
        bool val = gr < M;
#pragma unroll
        for (int i = 0; i < KD / 32; ++i) {
            int k0 = (sub + 4 * i) * 8;
            float4 x0 = make_float4(0.f, 0.f, 0.f, 0.f), x1 = x0;
            if (val) {
                x0 = *(const float4*)(Ap + k0);
                x1 = *(const float4*)(Ap + k0 + 4);
            }
            f16x8 hv;
            hv[0] = (_Float16)x0.x; hv[1] = (_Float16)x0.y;
            hv[2] = (_Float16)x0.z; hv[3] = (_Float16)x0.w;
            hv[4] = (_Float16)x1.x; hv[5] = (_Float16)x1.y;
            hv[6] = (_Float16)x1.z; hv[7] = (_Float16)x1.w;
            int ks = k0 ^ (8 * (r & 7));
            *(f16x8*)&As[r * KD + ks] = hv;
        }
    }
    __syncthreads();

    int colbase = wv * (ND / 4);
    int rL = L & 15;
    int kL = (L >> 4) * 8;

    f32x4 acc[4][NT_W] = {};
#pragma unroll
    for (int ks = 0; ks < KD; ks += 32) {
        f16x8 af[4];
#pragma unroll
        for (int mt = 0; mt < 4; ++mt) {
            int r = mt * 16 + rL;
            int k = (ks + kL) ^ (8 * (r & 7));
            af[mt] = *(const f16x8*)&As[r * KD + k];
        }
#pragma unroll
        for (int nt = 0; nt < NT_W; ++nt) {
            f16x8 bf = *(const f16x8*)(BT + (size_t)(colbase + nt * 16 + rL) * KD
                                       + ks + kL);
#pragma unroll
            for (int mt = 0; mt < 4; ++mt)
                acc[mt][nt] = __builtin_amdgcn_mfma_f32_16x16x32_f16(
                    af[mt], bf, acc[mt][nt], 0, 0, 0);
        }
    }

    // ---- epilogue: D[row=(L>>4)*4+j][col=L&15] per tile ----
    int cr0 = (L >> 4) * 4;
    int cc  = L & 15;
#pragma unroll
    for (int nt = 0; nt < NT_W; ++nt) {
        int col = colbase + nt * 16 + cc;
        float b = bias[col];
#pragma unroll
        for (int mt = 0; mt < 4; ++mt) {
#pragma unroll
            for (int j = 0; j < 4; ++j) {
                int R = row0 + mt * 16 + cr0 + j;
                if (R < M) {
                    float v = acc[mt][nt][j] + b;
                    if (QKV_EPI) {
                        if (col < 128) Cq[(size_t)R * 128 + col] = v;
                        else kv16[(size_t)R * 256 + (col - 128)] = __float2half(v);
                    } else {
                        Cq[(size_t)R * ND + col] = v;
                    }
                }
            }
        }
    }
}

// ---------------------------------------------------------------------------
// Counting sort of edges by dst: histogram -> 2-level exclusive scan -> scatter
// ---------------------------------------------------------------------------
__global__ void k_hist(const int* __restrict__ dst, int* __restrict__ deg, int e) {
    int i = blockIdx.x * 256 + threadIdx.x;
    if (i < e) atomicAdd(&deg[dst[i]], 1);
}

__global__ void k_scan1(const int* __restrict__ in, int* __restrict__ out,
                        int* __restrict__ bsums, int n) {
    __shared__ int sc[256];
    int t = threadIdx.x;
    int base = blockIdx.x * 1024 + t * 4;
    int v[4];
#pragma unroll
    for (int i = 0; i < 4; ++i) v[i] = (base + i < n) ? in[base + i] : 0;
    int tsum = v[0] + v[1] + v[2] + v[3];
    sc[t] = tsum;
    __syncthreads();
    for (int off = 1; off < 256; off <<= 1) {
        int x = 0;
        if (t >= off) x = sc[t - off];
        __syncthreads();
        sc[t] += x;
        __syncthreads();
    }
    int incl = sc[t];
    int e = incl - tsum;
#pragma unroll
    for (int i = 0; i < 4; ++i) {
        if (base + i < n) out[base + i] = e;
        e += v[i];
    }
    if (t == 255) bsums[blockIdx.x] = incl;
}

__global__ void k_scan2(int* __restrict__ bsums, int nb) {
    __shared__ int sc[256];
    int t = threadIdx.x;
    int v = (t < nb) ? bsums[t] : 0;
    sc[t] = v;
    __syncthreads();
    for (int off = 1; off < 256; off <<= 1) {
        int x = 0;
        if (t >= off) x = sc[t - off];
        __syncthreads();
        sc[t] += x;
        __syncthreads();
    }
    if (t < nb) bsums[t] = sc[t] - v;
}

__global__ void k_scan3(int* __restrict__ out, const int* __restrict__ bsums, int n) {
    int i = blockIdx.x * 256 + threadIdx.x;
    if (i < n) out[i] += bsums[blockIdx.x >> 2];
}

__global__ void k_scatter(const int* __restrict__ src, const int* __restrict__ dst,
                          const int* __restrict__ row_start, int* __restrict__ cursor,
                          int* __restrict__ sorted_src, int e) {
    int i = blockIdx.x * 256 + threadIdx.x;
    if (i < e) {
        int d  = dst[i];
        int p  = atomicAdd(&cursor[d], 1);
        sorted_src[row_start[d] + p] = src[i];
    }
}

// ---------------------------------------------------------------------------
// Fused SDDMM + edge-softmax + SPMM. One wave per dst node; k/v gathered as
// fp16. Chunked two-pass softmax.
// ---------------------------------------------------------------------------
__global__ __launch_bounds__(256) void edge_agg(
        const float* __restrict__ qbuf, const __half* __restrict__ kv16,
        const int* __restrict__ row_start, const int* __restrict__ deg,
        const int* __restrict__ sorted_src,
        float* __restrict__ agg, int nnodes) {
    __shared__ float sS[4][8][65];
    int wid  = threadIdx.x >> 6;
    int lane = threadIdx.x & 63;
    int node = blockIdx.x * 4 + wid;
    if (node >= nnodes) return;
    int h  = lane >> 3;
    int j0 = (lane & 7) * 8;
    float* srow = &sS[wid][h][0];

    const float2 qv = *(const float2*)(qbuf + (size_t)node * 128 + 2 * lane);
    float m = -INFINITY, z = 0.f, acc0 = 0.f, acc1 = 0.f;
    int rs = row_start[node];
    int dg = deg[node];

    for (int base = 0; base < dg; base += 64) {
        int nb = min(64, dg - base);
        int my_src = (base + lane < dg) ? sorted_src[rs + base + lane] : 0;

        // ---- pass A: scores -> LDS ----
#pragma unroll 4
        for (int j = 0; j < nb; ++j) {
            int sn = __shfl(my_src, j);
            float2 kv = __half22float2(
                *(const __half2*)(kv16 + (size_t)sn * 256 + 2 * lane));
            float p = kv.x * qv.x + kv.y * qv.y;
            p += __shfl_xor(p, 1);
            p += __shfl_xor(p, 2);
            p += __shfl_xor(p, 4);
            if ((lane & 7) == 0) srow[j] = p * 0.25f;   // 1/sqrt(16)
        }

        // ---- chunk softmax ----
        float sv[8];
        float cm = -INFINITY;
#pragma unroll
        for (int i = 0; i < 8; ++i) {
            sv[i] = (j0 + i < nb) ? srow[j0 + i] : -INFINITY;
            cm = fmaxf(cm, sv[i]);
        }
        cm = fmaxf(cm, __shfl_xor(cm, 1));
        cm = fmaxf(cm, __shfl_xor(cm, 2));
        cm = fmaxf(cm, __shfl_xor(cm, 4));
        float mn = fmaxf(m, cm);
        float zc = 0.f;
#pragma unroll
        for (int i = 0; i < 8; ++i) {
            float p = __expf(sv[i] - mn);
            srow[j0 + i] = p;
            zc += p;
        }
        zc += __shfl_xor(zc, 1);
        zc += __shfl_xor(zc, 2);
        zc += __shfl_xor(zc, 4);
        float f = __expf(m - mn);
        z = z * f + zc;
        acc0 *= f; acc1 *= f;
        m = mn;

        // ---- pass B: weighted V accumulate ----
#pragma unroll 4
        for (int j = 0; j < nb; ++j) {
            int sn = __shfl(my_src, j);
            float2 vv = __half22float2(
                *(const __half2*)(kv16 + (size_t)sn * 256 + 128 + 2 * lane));
            float w = srow[j];
            acc0 += w * vv.x;
            acc1 += w * vv.y;
        }
    }
    float inv = (z > 0.f) ? 1.f / z : 0.f;
    *(float2*)(agg + (size_t)node * OUT_F + 2 * lane) =
        make_float2(acc0 * inv, acc1 * inv);
}

// ---------------------------------------------------------------------------
extern "C" void kernel_launch(void* const* d_in, const int* in_sizes, int n_in,
                              void* d_out, int out_size, void* d_ws, size_t ws_size,
                              hipStream_t stream) {
    const float* h     = (const float*)d_in[0];
    const float* Wq    = (const float*)d_in[1];
    const float* bq    = (const float*)d_in[2];
    const float* Wk    = (const float*)d_in[3];
    const float* bk    = (const float*)d_in[4];
    const float* Wv    = (const float*)d_in[5];
    const float* bv    = (const float*)d_in[6];
    const float* Wmsg  = (const float*)d_in[7];
    const float* bmsg  = (const float*)d_in[8];
    const float* Wattn = (const float*)d_in[9];
    const float* battn = (const float*)d_in[10];
    const float* Wa    = (const float*)d_in[11];
    const float* ba    = (const float*)d_in[12];
    const int*   src   = (const int*)d_in[13];
    const int*   dst   = (const int*)d_in[14];
    float* out = (float*)d_out;

    int nn = in_sizes[0] / IN_F;   // 100000
    int ne = in_sizes[13];         // 1600000

    char* p = (char*)d_ws;
    auto carve = [&](size_t bytes) {
        char* r = p;
        p += (bytes + 255) & ~(size_t)255;
        return r;
    };
    _Float16* WT_all = (_Float16*)carve((size_t)QKV_F * IN_F * 2);
    _Float16* WaT    = (_Float16*)carve((size_t)OUT_F * OUT_F * 2);
    float*    b_all  = (float*)carve((size_t)QKV_F * 4);
    float*    qbuf   = (float*)carve((size_t)nn * 128 * 4);
    __half*   kv16   = (__half*)carve((size_t)nn * 256 * 2);
    float*    agg    = (float*)carve((size_t)nn * OUT_F * 4);
    int* deg     = (int*)carve((size_t)nn * 4);
    int* rowst   = (int*)carve((size_t)nn * 4);
    int* cursor  = (int*)carve((size_t)nn * 4);
    int* bsums   = (int*)carve(4096);
    int* ssrc    = (int*)carve((size_t)ne * 4);

    hipMemsetAsync(deg, 0, (size_t)nn * 4, stream);
    hipMemsetAsync(cursor, 0, (size_t)nn * 4, stream);

    prep_W<<<IN_F, QKV_F, 0, stream>>>(Wq, Wk, Wattn, Wv, Wmsg, WT_all);
    prep_b<<<1, QKV_F, 0, stream>>>(bq, bk, battn, bv, bmsg, Wattn, Wmsg, b_all);
    t_cast16<<<OUT_F, OUT_F, 0, stream>>>(Wa, WaT, OUT_F, OUT_F);

    // q (fp32) + k|v (fp16) = h @ W_all + b_all   [fp16 MFMA]
    mfma_gemm<IN_F, QKV_F, true><<<(nn + 63) / 64, 256, 0, stream>>>(
        h, WT_all, b_all, qbuf, kv16, nn);

    // counting sort edges by dst
    k_hist<<<(ne + 255) / 256, 256, 0, stream>>>(dst, deg, ne);
    int nb = (nn + 1023) / 1024;
    k_scan1<<<nb, 256, 0, stream>>>(deg, rowst, bsums, nn);
    k_scan2<<<1, 256, 0, stream>>>(bsums, nb);
    k_scan3<<<(nn + 255) / 256, 256, 0, stream>>>(rowst, bsums, nn);
    k_scatter<<<(ne + 255) / 256, 256, 0, stream>>>(src, dst, rowst, cursor, ssrc, ne);

    // fused SDDMM + softmax + SPMM
    edge_agg<<<(nn + 3) / 4, 256, 0, stream>>>(qbuf, kv16, rowst, deg, ssrc, agg, nn);

    // out = agg @ Wa + ba   [fp16 MFMA]
    mfma_gemm<OUT_F, OUT_F, false><<<(nn + 63) / 64, 256, 0, stream>>>(
        agg, WaT, ba, out, nullptr, nn);
}

// Round 7
// 610.036 us; speedup vs baseline: 1.4309x; 1.1694x over previous
//
#include <hip/hip_runtime.h>
#include <hip/hip_fp16.h>

#define IN_F 256
#define OUT_F 128
#define QKV_F 384   // fused q|k|v columns
#define HEADS 8
#define DKH 16

typedef _Float16 f16x8 __attribute__((ext_vector_type(8)));
typedef float    f32x4 __attribute__((ext_vector_type(4)));

// ---------------------------------------------------------------------------
// Weight folding: WT_all[384][256] (fp16, TRANSPOSED) = [Wq | Wk@Wattn | Wv@Wmsg]^T
// ---------------------------------------------------------------------------
__global__ void prep_W(const float* __restrict__ Wq,
                       const float* __restrict__ Wk, const float* __restrict__ Wattn,
                       const float* __restrict__ Wv, const float* __restrict__ Wmsg,
                       _Float16* __restrict__ WT_all) {
    int k = blockIdx.x;      // 0..255 (input dim)
    int c = threadIdx.x;     // 0..383 (output col)
    float r;
    if (c < 128) {
        r = Wq[k * 128 + c];
    } else if (c < 256) {
        int cc = c - 128;
        float s = 0.f;
        for (int j = 0; j < 128; ++j) s += Wk[k * 128 + j] * Wattn[j * 128 + cc];
        r = s;
    } else {
        int cc = c - 256;
        float s = 0.f;
        for (int j = 0; j < 128; ++j) s += Wv[k * 128 + j] * Wmsg[j * 128 + cc];
        r = s;
    }
    WT_all[(size_t)c * IN_F + k] = (_Float16)r;   // transposed store
}

__global__ void prep_b(const float* __restrict__ bq, const float* __restrict__ bk,
                       const float* __restrict__ battn, const float* __restrict__ bv,
                       const float* __restrict__ bmsg, const float* __restrict__ Wattn,
                       const float* __restrict__ Wmsg, float* __restrict__ b_all) {
    int c = threadIdx.x;     // 0..383
    float r;
    if (c < 128) {
        r = bq[c];
    } else if (c < 256) {
        int cc = c - 128;
        float s = battn[cc];
        for (int j = 0; j < 128; ++j) s += bk[j] * Wattn[j * 128 + cc];
        r = s;
    } else {
        int cc = c - 256;
        float s = bmsg[cc];
        for (int j = 0; j < 128; ++j) s += bv[j] * Wmsg[j * 128 + cc];
        r = s;
    }
    b_all[c] = r;
}

// transpose + cast fp32 W[K][N] -> fp16 WT[N][K]
__global__ void t_cast16(const float* __restrict__ W, _Float16* __restrict__ WT,
                         int K, int N) {
    int k = blockIdx.x;
    int c = threadIdx.x;
    WT[(size_t)c * K + k] = (_Float16)W[(size_t)k * N + c];
}

// ---------------------------------------------------------------------------
// fp16-MFMA GEMM: C[M,ND] = A[M,KD](fp32, cast on stage) @ BT[ND,KD](fp16) + bias
// (unchanged from round 5 — verified)
// ---------------------------------------------------------------------------
template<int KD, int ND, bool QKV_EPI>
__global__ __launch_bounds__(256) void mfma_gemm(
        const float* __restrict__ A, const _Float16* __restrict__ BT,
        const float* __restrict__ bias, float* __restrict__ Cq,
        __half* __restrict__ kv16, int M) {
    constexpr int BMR  = 64;
    constexpr int NT_W = ND / 64;
    __shared__ __align__(16) _Float16 As[BMR * KD];

    int t   = threadIdx.x;
    int wv  = t >> 6;
    int L   = t & 63;
    int row0 = blockIdx.x * BMR;

    {
        int r   = t >> 2;
        int sub = t & 3;
        int gr  = row0 + r;
        const float* Ap = A + (size_t)gr * KD;
        bool val = gr < M;
#pragma unroll
        for (int i = 0; i < KD / 32; ++i) {
            int k0 = (sub + 4 * i) * 8;
            float4 x0 = make_float4(0.f, 0.f, 0.f, 0.f), x1 = x0;
            if (val) {
                x0 = *(const float4*)(Ap + k0);
                x1 = *(const float4*)(Ap + k0 + 4);
            }
            f16x8 hv;
            hv[0] = (_Float16)x0.x; hv[1] = (_Float16)x0.y;
            hv[2] = (_Float16)x0.z; hv[3] = (_Float16)x0.w;
            hv[4] = (_Float16)x1.x; hv[5] = (_Float16)x1.y;
            hv[6] = (_Float16)x1.z; hv[7] = (_Float16)x1.w;
            int ks = k0 ^ (8 * (r & 7));
            *(f16x8*)&As[r * KD + ks] = hv;
        }
    }
    __syncthreads();

    int colbase = wv * (ND / 4);
    int rL = L & 15;
    int kL = (L >> 4) * 8;

    f32x4 acc[4][NT_W] = {};
#pragma unroll
    for (int ks = 0; ks < KD; ks += 32) {
        f16x8 af[4];
#pragma unroll
        for (int mt = 0; mt < 4; ++mt) {
            int r = mt * 16 + rL;
            int k = (ks + kL) ^ (8 * (r & 7));
            af[mt] = *(const f16x8*)&As[r * KD + k];
        }
#pragma unroll
        for (int nt = 0; nt < NT_W; ++nt) {
            f16x8 bf = *(const f16x8*)(BT + (size_t)(colbase + nt * 16 + rL) * KD
                                       + ks + kL);
#pragma unroll
            for (int mt = 0; mt < 4; ++mt)
                acc[mt][nt] = __builtin_amdgcn_mfma_f32_16x16x32_f16(
                    af[mt], bf, acc[mt][nt], 0, 0, 0);
        }
    }

    int cr0 = (L >> 4) * 4;
    int cc  = L & 15;
#pragma unroll
    for (int nt = 0; nt < NT_W; ++nt) {
        int col = colbase + nt * 16 + cc;
        float b = bias[col];
#pragma unroll
        for (int mt = 0; mt < 4; ++mt) {
#pragma unroll
            for (int j = 0; j < 4; ++j) {
                int R = row0 + mt * 16 + cr0 + j;
                if (R < M) {
                    float v = acc[mt][nt][j] + b;
                    if (QKV_EPI) {
                        if (col < 128) Cq[(size_t)R * 128 + col] = v;
                        else kv16[(size_t)R * 256 + (col - 128)] = __float2half(v);
                    } else {
                        Cq[(size_t)R * ND + col] = v;
                    }
                }
            }
        }
    }
}

// ---------------------------------------------------------------------------
// Counting sort of edges by dst: histogram -> 2-level exclusive scan -> scatter
// ---------------------------------------------------------------------------
__global__ void k_hist(const int* __restrict__ dst, int* __restrict__ deg, int e) {
    int i = blockIdx.x * 256 + threadIdx.x;
    if (i < e) atomicAdd(&deg[dst[i]], 1);
}

__global__ void k_scan1(const int* __restrict__ in, int* __restrict__ out,
                        int* __restrict__ bsums, int n) {
    __shared__ int sc[256];
    int t = threadIdx.x;
    int base = blockIdx.x * 1024 + t * 4;
    int v[4];
#pragma unroll
    for (int i = 0; i < 4; ++i) v[i] = (base + i < n) ? in[base + i] : 0;
    int tsum = v[0] + v[1] + v[2] + v[3];
    sc[t] = tsum;
    __syncthreads();
    for (int off = 1; off < 256; off <<= 1) {
        int x = 0;
        if (t >= off) x = sc[t - off];
        __syncthreads();
        sc[t] += x;
        __syncthreads();
    }
    int incl = sc[t];
    int e = incl - tsum;
#pragma unroll
    for (int i = 0; i < 4; ++i) {
        if (base + i < n) out[base + i] = e;
        e += v[i];
    }
    if (t == 255) bsums[blockIdx.x] = incl;
}

__global__ void k_scan2(int* __restrict__ bsums, int nb) {
    __shared__ int sc[256];
    int t = threadIdx.x;
    int v = (t < nb) ? bsums[t] : 0;
    sc[t] = v;
    __syncthreads();
    for (int off = 1; off < 256; off <<= 1) {
        int x = 0;
        if (t >= off) x = sc[t - off];
        __syncthreads();
        sc[t] += x;
        __syncthreads();
    }
    if (t < nb) bsums[t] = sc[t] - v;
}

__global__ void k_scan3(int* __restrict__ out, const int* __restrict__ bsums, int n) {
    int i = blockIdx.x * 256 + threadIdx.x;
    if (i < n) out[i] += bsums[blockIdx.x >> 2];
}

__global__ void k_scatter(const int* __restrict__ src, const int* __restrict__ dst,
                          const int* __restrict__ row_start, int* __restrict__ cursor,
                          int* __restrict__ sorted_src, int e) {
    int i = blockIdx.x * 256 + threadIdx.x;
    if (i < e) {
        int d  = dst[i];
        int p  = atomicAdd(&cursor[d], 1);
        sorted_src[row_start[d] + p] = src[i];
    }
}

// ---------------------------------------------------------------------------
// Fused SDDMM + edge-softmax + SPMM. One wave per dst node.
// v3: ONE-PASS register pipeline, chunk = 16 edges.
//   - all 32 loads (16 k-half2 + 16 v-half2) issued into register arrays
//     before any use: ~8KB in flight per wave (latency -> BW bound).
//   - row index scalarized via readlane -> uniform-base + lane-voffset loads.
//   - after the 3x shfl_xor dot-reduce, every lane holds all 16 scores of its
//     head in registers -> chunk softmax is per-lane private; v consumed from
//     registers. No LDS, no second gather pass.
//   - tail masked with s[j] = -INF -> w = 0.
// ---------------------------------------------------------------------------
__global__ __launch_bounds__(256) void edge_agg(
        const float* __restrict__ qbuf, const __half* __restrict__ kv16,
        const int* __restrict__ row_start, const int* __restrict__ deg,
        const int* __restrict__ sorted_src,
        float* __restrict__ agg, int nnodes) {
    int wid  = threadIdx.x >> 6;
    int lane = threadIdx.x & 63;
    int node = blockIdx.x * 4 + wid;
    if (node >= nnodes) return;

    const float2 qv = *(const float2*)(qbuf + (size_t)node * 128 + 2 * lane);
    float m = -INFINITY, z = 0.f, acc0 = 0.f, acc1 = 0.f;
    int rs = row_start[node];
    int dg = deg[node];

    for (int base = 0; base < dg; base += 16) {
        int rem = dg - base;   // >= 1
        int my_src = (lane < 16 && base + lane < dg) ? sorted_src[rs + base + lane] : 0;

        unsigned int kbits[16], vbits[16];
#pragma unroll
        for (int j = 0; j < 16; ++j) {
            int sn = __builtin_amdgcn_readlane(my_src, j);   // uniform row idx
            const __half* rowp = kv16 + (size_t)sn * 256 + 2 * lane;
            kbits[j] = *(const unsigned int*)rowp;           // k half2
            vbits[j] = *(const unsigned int*)(rowp + 128);   // v half2
        }

        float s[16];
#pragma unroll
        for (int j = 0; j < 16; ++j) {
            float2 kf = __half22float2(*(const __half2*)&kbits[j]);
            float pp = kf.x * qv.x + kf.y * qv.y;
            pp += __shfl_xor(pp, 1);
            pp += __shfl_xor(pp, 2);
            pp += __shfl_xor(pp, 4);     // all 8 lanes of head group hold dot
            s[j] = (j < rem) ? pp * 0.25f : -INFINITY;   // 1/sqrt(16); tail->w=0
        }

        float cm = s[0];
#pragma unroll
        for (int j = 1; j < 16; ++j) cm = fmaxf(cm, s[j]);
        float mn = fmaxf(m, cm);
        float f  = __expf(m - mn);       // first chunk: exp(-inf)=0
        acc0 *= f; acc1 *= f;
        float zc = 0.f;
#pragma unroll
        for (int j = 0; j < 16; ++j) {
            float w = __expf(s[j] - mn);
            zc += w;
            float2 vf = __half22float2(*(const __half2*)&vbits[j]);
            acc0 = fmaf(w, vf.x, acc0);
            acc1 = fmaf(w, vf.y, acc1);
        }
        z = z * f + zc;
        m = mn;
    }
    float inv = (z > 0.f) ? 1.f / z : 0.f;   // deg-0 node -> zeros
    *(float2*)(agg + (size_t)node * OUT_F + 2 * lane) =
        make_float2(acc0 * inv, acc1 * inv);
}

// ---------------------------------------------------------------------------
extern "C" void kernel_launch(void* const* d_in, const int* in_sizes, int n_in,
                              void* d_out, int out_size, void* d_ws, size_t ws_size,
                              hipStream_t stream) {
    const float* h     = (const float*)d_in[0];
    const float* Wq    = (const float*)d_in[1];
    const float* bq    = (const float*)d_in[2];
    const float* Wk    = (const float*)d_in[3];
    const float* bk    = (const float*)d_in[4];
    const float* Wv    = (const float*)d_in[5];
    const float* bv    = (const float*)d_in[6];
    const float* Wmsg  = (const float*)d_in[7];
    const float* bmsg  = (const float*)d_in[8];
    const float* Wattn = (const float*)d_in[9];
    const float* battn = (const float*)d_in[10];
    const float* Wa    = (const float*)d_in[11];
    const float* ba    = (const float*)d_in[12];
    const int*   src   = (const int*)d_in[13];
    const int*   dst   = (const int*)d_in[14];
    float* out = (float*)d_out;

    int nn = in_sizes[0] / IN_F;   // 100000
    int ne = in_sizes[13];         // 1600000

    char* p = (char*)d_ws;
    auto carve = [&](size_t bytes) {
        char* r = p;
        p += (bytes + 255) & ~(size_t)255;
        return r;
    };
    _Float16* WT_all = (_Float16*)carve((size_t)QKV_F * IN_F * 2);
    _Float16* WaT    = (_Float16*)carve((size_t)OUT_F * OUT_F * 2);
    float*    b_all  = (float*)carve((size_t)QKV_F * 4);
    float*    qbuf   = (float*)carve((size_t)nn * 128 * 4);
    __half*   kv16   = (__half*)carve((size_t)nn * 256 * 2);
    float*    agg    = (float*)carve((size_t)nn * OUT_F * 4);
    int* deg     = (int*)carve((size_t)nn * 4);
    int* rowst   = (int*)carve((size_t)nn * 4);
    int* cursor  = (int*)carve((size_t)nn * 4);
    int* bsums   = (int*)carve(4096);
    int* ssrc    = (int*)carve((size_t)ne * 4);

    hipMemsetAsync(deg, 0, (size_t)nn * 4, stream);
    hipMemsetAsync(cursor, 0, (size_t)nn * 4, stream);

    prep_W<<<IN_F, QKV_F, 0, stream>>>(Wq, Wk, Wattn, Wv, Wmsg, WT_all);
    prep_b<<<1, QKV_F, 0, stream>>>(bq, bk, battn, bv, bmsg, Wattn, Wmsg, b_all);
    t_cast16<<<OUT_F, OUT_F, 0, stream>>>(Wa, WaT, OUT_F, OUT_F);

    // q (fp32) + k|v (fp16) = h @ W_all + b_all   [fp16 MFMA]
    mfma_gemm<IN_F, QKV_F, true><<<(nn + 63) / 64, 256, 0, stream>>>(
        h, WT_all, b_all, qbuf, kv16, nn);

    // counting sort edges by dst
    k_hist<<<(ne + 255) / 256, 256, 0, stream>>>(dst, deg, ne);
    int nb = (nn + 1023) / 1024;
    k_scan1<<<nb, 256, 0, stream>>>(deg, rowst, bsums, nn);
    k_scan2<<<1, 256, 0, stream>>>(bsums, nb);
    k_scan3<<<(nn + 255) / 256, 256, 0, stream>>>(rowst, bsums, nn);
    k_scatter<<<(ne + 255) / 256, 256, 0, stream>>>(src, dst, rowst, cursor, ssrc, ne);

    // fused SDDMM + softmax + SPMM
    edge_agg<<<(nn + 3) / 4, 256, 0, stream>>>(qbuf, kv16, rowst, deg, ssrc, agg, nn);

    // out = agg @ Wa + ba   [fp16 MFMA]
    mfma_gemm<OUT_F, OUT_F, false><<<(nn + 63) / 64, 256, 0, stream>>>(
        agg, WaT, ba, out, nullptr, nn);
}

// Round 10
// 568.790 us; speedup vs baseline: 1.5347x; 1.0725x over previous
//
#include <hip/hip_runtime.h>
#include <hip/hip_fp16.h>

#define IN_F 256
#define OUT_F 128
#define QKV_F 384   // fused q|k|v columns
#define HEADS 8
#define DKH 16

typedef _Float16 f16x8 __attribute__((ext_vector_type(8)));
typedef float    f32x4 __attribute__((ext_vector_type(4)));

// ---------------------------------------------------------------------------
// Weight folding: WT_all[384][256] (fp16, TRANSPOSED) = [Wq | Wk@Wattn | Wv@Wmsg]^T
// ---------------------------------------------------------------------------
__global__ void prep_W(const float* __restrict__ Wq,
                       const float* __restrict__ Wk, const float* __restrict__ Wattn,
                       const float* __restrict__ Wv, const float* __restrict__ Wmsg,
                       _Float16* __restrict__ WT_all) {
    int k = blockIdx.x;      // 0..255 (input dim)
    int c = threadIdx.x;     // 0..383 (output col)
    float r;
    if (c < 128) {
        r = Wq[k * 128 + c];
    } else if (c < 256) {
        int cc = c - 128;
        float s = 0.f;
        for (int j = 0; j < 128; ++j) s += Wk[k * 128 + j] * Wattn[j * 128 + cc];
        r = s;
    } else {
        int cc = c - 256;
        float s = 0.f;
        for (int j = 0; j < 128; ++j) s += Wv[k * 128 + j] * Wmsg[j * 128 + cc];
        r = s;
    }
    WT_all[(size_t)c * IN_F + k] = (_Float16)r;   // transposed store
}

__global__ void prep_b(const float* __restrict__ bq, const float* __restrict__ bk,
                       const float* __restrict__ battn, const float* __restrict__ bv,
                       const float* __restrict__ bmsg, const float* __restrict__ Wattn,
                       const float* __restrict__ Wmsg, float* __restrict__ b_all) {
    int c = threadIdx.x;     // 0..383
    float r;
    if (c < 128) {
        r = bq[c];
    } else if (c < 256) {
        int cc = c - 128;
        float s = battn[cc];
        for (int j = 0; j < 128; ++j) s += bk[j] * Wattn[j * 128 + cc];
        r = s;
    } else {
        int cc = c - 256;
        float s = bmsg[cc];
        for (int j = 0; j < 128; ++j) s += bv[j] * Wmsg[j * 128 + cc];
        r = s;
    }
    b_all[c] = r;
}

// transpose + cast fp32 W[K][N] -> fp16 WT[N][K]
__global__ void t_cast16(const float* __restrict__ W, _Float16* __restrict__ WT,
                         int K, int N) {
    int k = blockIdx.x;
    int c = threadIdx.x;
    WT[(size_t)c * K + k] = (_Float16)W[(size_t)k * N + c];
}

// ---------------------------------------------------------------------------
// fp16-MFMA GEMM, B WEIGHT-STATIONARY in registers.
// Block: 256 thr (4 waves). Wave w owns 32 cols: colbase = blockIdx.y*128+w*32.
// Breg[2][KD/32] (f16x8 each) loaded ONCE per block; blocks persistent over
// 64-row tiles (grid-stride). Inner K-loop: ds_read_b128 (A frags, swizzled)
// + MFMA only — no global loads on the critical path.
// A staged fp32->fp16 to LDS with XOR swizzle (k ^= 8*(r&7) halfwords):
// fragment reads 2-way bank alias only (free).
// QKV epilogue: col<128 -> q fp32 [M][128]; col>=128 -> kv fp16 [M][256].
// ---------------------------------------------------------------------------
template<int KD, bool QKV_EPI>
__global__ __launch_bounds__(256) void mfma_gemm(
        const float* __restrict__ A, const _Float16* __restrict__ BT,
        const float* __restrict__ bias, float* __restrict__ Cq,
        __half* __restrict__ kv16, int M, int ntiles, int nrowblk) {
    constexpr int NKQ = KD / 32;
    __shared__ __align__(16) _Float16 As[64 * KD];

    int t  = threadIdx.x;
    int wv = t >> 6;
    int L  = t & 63;
    int rL = L & 15;
    int kL = (L >> 4) * 8;
    int colbase = blockIdx.y * 128 + wv * 32;

    // ---- B into registers, once ----
    f16x8 Breg[2][NKQ];
#pragma unroll
    for (int nt = 0; nt < 2; ++nt)
#pragma unroll
        for (int kq = 0; kq < NKQ; ++kq)
            Breg[nt][kq] = *(const f16x8*)(
                BT + (size_t)(colbase + nt * 16 + rL) * KD + kq * 32 + kL);

    float bb[2] = { bias[colbase + rL], bias[colbase + 16 + rL] };

    int r_  = t >> 2;      // stage row 0..63
    int sub = t & 3;

    for (int rt = blockIdx.x; rt < ntiles; rt += nrowblk) {
        int row0 = rt * 64;

        // ---- stage A tile: fp32 -> fp16, swizzled ----
        {
            int gr = row0 + r_;
            const float* Ap = A + (size_t)gr * KD;
            bool val = gr < M;
#pragma unroll
            for (int i = 0; i < NKQ; ++i) {
                int k0 = (sub + 4 * i) * 8;
                float4 x0 = make_float4(0.f, 0.f, 0.f, 0.f), x1 = x0;
                if (val) {
                    x0 = *(const float4*)(Ap + k0);
                    x1 = *(const float4*)(Ap + k0 + 4);
                }
                f16x8 hv;
                hv[0] = (_Float16)x0.x; hv[1] = (_Float16)x0.y;
                hv[2] = (_Float16)x0.z; hv[3] = (_Float16)x0.w;
                hv[4] = (_Float16)x1.x; hv[5] = (_Float16)x1.y;
                hv[6] = (_Float16)x1.z; hv[7] = (_Float16)x1.w;
                int ks = k0 ^ (8 * (r_ & 7));
                *(f16x8*)&As[r_ * KD + ks] = hv;
            }
        }
        __syncthreads();

        // ---- K-loop: LDS + regs only ----
        f32x4 acc[4][2] = {};
#pragma unroll
        for (int kq = 0; kq < NKQ; ++kq) {
            int ksk = kq * 32 + kL;
            f16x8 af[4];
#pragma unroll
            for (int mt = 0; mt < 4; ++mt) {
                int r = mt * 16 + rL;
                int k = ksk ^ (8 * (r & 7));
                af[mt] = *(const f16x8*)&As[r * KD + k];
            }
#pragma unroll
            for (int mt = 0; mt < 4; ++mt) {
                acc[mt][0] = __builtin_amdgcn_mfma_f32_16x16x32_f16(
                    af[mt], Breg[0][kq], acc[mt][0], 0, 0, 0);
                acc[mt][1] = __builtin_amdgcn_mfma_f32_16x16x32_f16(
                    af[mt], Breg[1][kq], acc[mt][1], 0, 0, 0);
            }
        }
        __syncthreads();   // all LDS reads done before next tile's stage

        // ---- epilogue ----
        int cr0 = (L >> 4) * 4;
#pragma unroll
        for (int nt = 0; nt < 2; ++nt) {
            int col = colbase + nt * 16 + rL;
#pragma unroll
            for (int mt = 0; mt < 4; ++mt)
#pragma unroll
                for (int j = 0; j < 4; ++j) {
                    int R = row0 + mt * 16 + cr0 + j;
                    if (R < M) {
                        float v = acc[mt][nt][j] + bb[nt];
                        if (QKV_EPI) {
                            if (col < 128) Cq[(size_t)R * 128 + col] = v;
                            else kv16[(size_t)R * 256 + (col - 128)] = __float2half(v);
                        } else {
                            Cq[(size_t)R * 128 + col] = v;
                        }
                    }
                }
        }
    }
}

// ---------------------------------------------------------------------------
// Counting sort of edges by dst: histogram -> 2-level exclusive scan -> scatter
// ---------------------------------------------------------------------------
__global__ void k_hist(const int* __restrict__ dst, int* __restrict__ deg, int e) {
    int i = blockIdx.x * 256 + threadIdx.x;
    if (i < e) atomicAdd(&deg[dst[i]], 1);
}

__global__ void k_scan1(const int* __restrict__ in, int* __restrict__ out,
                        int* __restrict__ bsums, int n) {
    __shared__ int sc[256];
    int t = threadIdx.x;
    int base = blockIdx.x * 1024 + t * 4;
    int v[4];
#pragma unroll
    for (int i = 0; i < 4; ++i) v[i] = (base + i < n) ? in[base + i] : 0;
    int tsum = v[0] + v[1] + v[2] + v[3];
    sc[t] = tsum;
    __syncthreads();
    for (int off = 1; off < 256; off <<= 1) {
        int x = 0;
        if (t >= off) x = sc[t - off];
        __syncthreads();
        sc[t] += x;
        __syncthreads();
    }
    int incl = sc[t];
    int e = incl - tsum;
#pragma unroll
    for (int i = 0; i < 4; ++i) {
        if (base + i < n) out[base + i] = e;
        e += v[i];
    }
    if (t == 255) bsums[blockIdx.x] = incl;
}

__global__ void k_scan2(int* __restrict__ bsums, int nb) {
    __shared__ int sc[256];
    int t = threadIdx.x;
    int v = (t < nb) ? bsums[t] : 0;
    sc[t] = v;
    __syncthreads();
    for (int off = 1; off < 256; off <<= 1) {
        int x = 0;
        if (t >= off) x = sc[t - off];
        __syncthreads();
        sc[t] += x;
        __syncthreads();
    }
    if (t < nb) bsums[t] = sc[t] - v;
}

__global__ void k_scan3(int* __restrict__ out, const int* __restrict__ bsums, int n) {
    int i = blockIdx.x * 256 + threadIdx.x;
    if (i < n) out[i] += bsums[blockIdx.x >> 2];
}

__global__ void k_scatter(const int* __restrict__ src, const int* __restrict__ dst,
                          const int* __restrict__ row_start, int* __restrict__ cursor,
                          int* __restrict__ sorted_src, int e) {
    int i = blockIdx.x * 256 + threadIdx.x;
    if (i < e) {
        int d  = dst[i];
        int p  = atomicAdd(&cursor[d], 1);
        sorted_src[row_start[d] + p] = src[i];
    }
}

// ---------------------------------------------------------------------------
// Fused SDDMM + edge-softmax + SPMM. One wave per dst node.
// One-pass register pipeline, chunk = 16 edges (unchanged from round 6).
// ---------------------------------------------------------------------------
__global__ __launch_bounds__(256) void edge_agg(
        const float* __restrict__ qbuf, const __half* __restrict__ kv16,
        const int* __restrict__ row_start, const int* __restrict__ deg,
        const int* __restrict__ sorted_src,
        float* __restrict__ agg, int nnodes) {
    int wid  = threadIdx.x >> 6;
    int lane = threadIdx.x & 63;
    int node = blockIdx.x * 4 + wid;
    if (node >= nnodes) return;

    const float2 qv = *(const float2*)(qbuf + (size_t)node * 128 + 2 * lane);
    float m = -INFINITY, z = 0.f, acc0 = 0.f, acc1 = 0.f;
    int rs = row_start[node];
    int dg = deg[node];

    for (int base = 0; base < dg; base += 16) {
        int rem = dg - base;   // >= 1
        int my_src = (lane < 16 && base + lane < dg) ? sorted_src[rs + base + lane] : 0;

        unsigned int kbits[16], vbits[16];
#pragma unroll
        for (int j = 0; j < 16; ++j) {
            int sn = __builtin_amdgcn_readlane(my_src, j);   // uniform row idx
            const __half* rowp = kv16 + (size_t)sn * 256 + 2 * lane;
            kbits[j] = *(const unsigned int*)rowp;           // k half2
            vbits[j] = *(const unsigned int*)(rowp + 128);   // v half2
        }

        float s[16];
#pragma unroll
        for (int j = 0; j < 16; ++j) {
            float2 kf = __half22float2(*(const __half2*)&kbits[j]);
            float pp = kf.x * qv.x + kf.y * qv.y;
            pp += __shfl_xor(pp, 1);
            pp += __shfl_xor(pp, 2);
            pp += __shfl_xor(pp, 4);     // all 8 lanes of head group hold dot
            s[j] = (j < rem) ? pp * 0.25f : -INFINITY;   // 1/sqrt(16); tail->w=0
        }

        float cm = s[0];
#pragma unroll
        for (int j = 1; j < 16; ++j) cm = fmaxf(cm, s[j]);
        float mn = fmaxf(m, cm);
        float f  = __expf(m - mn);       // first chunk: exp(-inf)=0
        acc0 *= f; acc1 *= f;
        float zc = 0.f;
#pragma unroll
        for (int j = 0; j < 16; ++j) {
            float w = __expf(s[j] - mn);
            zc += w;
            float2 vf = __half22float2(*(const __half2*)&vbits[j]);
            acc0 = fmaf(w, vf.x, acc0);
            acc1 = fmaf(w, vf.y, acc1);
        }
        z = z * f + zc;
        m = mn;
    }
    float inv = (z > 0.f) ? 1.f / z : 0.f;   // deg-0 node -> zeros
    *(float2*)(agg + (size_t)node * OUT_F + 2 * lane) =
        make_float2(acc0 * inv, acc1 * inv);
}

// ---------------------------------------------------------------------------
extern "C" void kernel_launch(void* const* d_in, const int* in_sizes, int n_in,
                              void* d_out, int out_size, void* d_ws, size_t ws_size,
                              hipStream_t stream) {
    const float* h     = (const float*)d_in[0];
    const float* Wq    = (const float*)d_in[1];
    const float* bq    = (const float*)d_in[2];
    const float* Wk    = (const float*)d_in[3];
    const float* bk    = (const float*)d_in[4];
    const float* Wv    = (const float*)d_in[5];
    const float* bv    = (const float*)d_in[6];
    const float* Wmsg  = (const float*)d_in[7];
    const float* bmsg  = (const float*)d_in[8];
    const float* Wattn = (const float*)d_in[9];
    const float* battn = (const float*)d_in[10];
    const float* Wa    = (const float*)d_in[11];
    const float* ba    = (const float*)d_in[12];
    const int*   src   = (const int*)d_in[13];
    const int*   dst   = (const int*)d_in[14];
    float* out = (float*)d_out;

    int nn = in_sizes[0] / IN_F;   // 100000
    int ne = in_sizes[13];         // 1600000

    char* p = (char*)d_ws;
    auto carve = [&](size_t bytes) {
        char* r = p;
        p += (bytes + 255) & ~(size_t)255;
        return r;
    };
    _Float16* WT_all = (_Float16*)carve((size_t)QKV_F * IN_F * 2);
    _Float16* WaT    = (_Float16*)carve((size_t)OUT_F * OUT_F * 2);
    float*    b_all  = (float*)carve((size_t)QKV_F * 4);
    float*    qbuf   = (float*)carve((size_t)nn * 128 * 4);
    __half*   kv16   = (__half*)carve((size_t)nn * 256 * 2);
    float*    agg    = (float*)carve((size_t)nn * OUT_F * 4);
    int* deg     = (int*)carve((size_t)nn * 4);
    int* rowst   = (int*)carve((size_t)nn * 4);
    int* cursor  = (int*)carve((size_t)nn * 4);
    int* bsums   = (int*)carve(4096);
    int* ssrc    = (int*)carve((size_t)ne * 4);

    hipMemsetAsync(deg, 0, (size_t)nn * 4, stream);
    hipMemsetAsync(cursor, 0, (size_t)nn * 4, stream);

    prep_W<<<IN_F, QKV_F, 0, stream>>>(Wq, Wk, Wattn, Wv, Wmsg, WT_all);
    prep_b<<<1, QKV_F, 0, stream>>>(bq, bk, battn, bv, bmsg, Wattn, Wmsg, b_all);
    t_cast16<<<OUT_F, OUT_F, 0, stream>>>(Wa, WaT, OUT_F, OUT_F);

    int ntiles = (nn + 63) / 64;             // 64-row tiles

    // q (fp32) + k|v (fp16) = h @ W_all + b_all   [fp16 MFMA, B-stationary]
    {
        int nrb = ntiles < 176 ? ntiles : 176;   // ~2 blocks/CU incl. 3 col groups
        mfma_gemm<IN_F, true><<<dim3(nrb, QKV_F / 128), 256, 0, stream>>>(
            h, WT_all, b_all, qbuf, kv16, nn, ntiles, nrb);
    }

    // counting sort edges by dst
    k_hist<<<(ne + 255) / 256, 256, 0, stream>>>(dst, deg, ne);
    int nb = (nn + 1023) / 1024;
    k_scan1<<<nb, 256, 0, stream>>>(deg, rowst, bsums, nn);
    k_scan2<<<1, 256, 0, stream>>>(bsums, nb);
    k_scan3<<<(nn + 255) / 256, 256, 0, stream>>>(rowst, bsums, nn);
    k_scatter<<<(ne + 255) / 256, 256, 0, stream>>>(src, dst, rowst, cursor, ssrc, ne);

    // fused SDDMM + softmax + SPMM
    edge_agg<<<(nn + 3) / 4, 256, 0, stream>>>(qbuf, kv16, rowst, deg, ssrc, agg, nn);

    // out = agg @ Wa + ba   [fp16 MFMA, B-stationary]
    {
        int nrb = ntiles < 512 ? ntiles : 512;
        mfma_gemm<OUT_F, false><<<dim3(nrb, 1), 256, 0, stream>>>(
            agg, WaT, ba, out, nullptr, nn, ntiles, nrb);
    }
}

// Round 13
// 565.527 us; speedup vs baseline: 1.5435x; 1.0058x over previous
//
#include <hip/hip_runtime.h>
#include <hip/hip_fp16.h>

#define IN_F 256
#define OUT_F 128
#define QKV_F 384   // fused q|k|v columns
#define HEADS 8
#define DKH 16

typedef _Float16 f16x8 __attribute__((ext_vector_type(8)));
typedef _Float16 f16x2 __attribute__((ext_vector_type(2)));
typedef float    f32x4 __attribute__((ext_vector_type(4)));

// ---------------------------------------------------------------------------
// Weight folding: WT_all[384][256] (fp16, TRANSPOSED) = [Wq | Wk@Wattn | Wv@Wmsg]^T
// ---------------------------------------------------------------------------
__global__ void prep_W(const float* __restrict__ Wq,
                       const float* __restrict__ Wk, const float* __restrict__ Wattn,
                       const float* __restrict__ Wv, const float* __restrict__ Wmsg,
                       _Float16* __restrict__ WT_all) {
    int k = blockIdx.x;      // 0..255 (input dim)
    int c = threadIdx.x;     // 0..383 (output col)
    float r;
    if (c < 128) {
        r = Wq[k * 128 + c];
    } else if (c < 256) {
        int cc = c - 128;
        float s = 0.f;
        for (int j = 0; j < 128; ++j) s += Wk[k * 128 + j] * Wattn[j * 128 + cc];
        r = s;
    } else {
        int cc = c - 256;
        float s = 0.f;
        for (int j = 0; j < 128; ++j) s += Wv[k * 128 + j] * Wmsg[j * 128 + cc];
        r = s;
    }
    WT_all[(size_t)c * IN_F + k] = (_Float16)r;   // transposed store
}

__global__ void prep_b(const float* __restrict__ bq, const float* __restrict__ bk,
                       const float* __restrict__ battn, const float* __restrict__ bv,
                       const float* __restrict__ bmsg, const float* __restrict__ Wattn,
                       const float* __restrict__ Wmsg, float* __restrict__ b_all) {
    int c = threadIdx.x;     // 0..383
    float r;
    if (c < 128) {
        r = bq[c];
    } else if (c < 256) {
        int cc = c - 128;
        float s = battn[cc];
        for (int j = 0; j < 128; ++j) s += bk[j] * Wattn[j * 128 + cc];
        r = s;
    } else {
        int cc = c - 256;
        float s = bmsg[cc];
        for (int j = 0; j < 128; ++j) s += bv[j] * Wmsg[j * 128 + cc];
        r = s;
    }
    b_all[c] = r;
}

// transpose + cast fp32 W[K][N] -> fp16 WT[N][K]
__global__ void t_cast16(const float* __restrict__ W, _Float16* __restrict__ WT,
                         int K, int N) {
    int k = blockIdx.x;
    int c = threadIdx.x;
    WT[(size_t)c * K + k] = (_Float16)W[(size_t)k * N + c];
}

// ---------------------------------------------------------------------------
// fp16-MFMA GEMM, B WEIGHT-STATIONARY in registers (verified round 10).
// QKV epilogue: col<128 -> q fp16 [M][128]; col>=128 -> kv fp16 [M][256].
// ---------------------------------------------------------------------------
template<int KD, bool QKV_EPI>
__global__ __launch_bounds__(256) void mfma_gemm(
        const float* __restrict__ A, const _Float16* __restrict__ BT,
        const float* __restrict__ bias, float* __restrict__ Cq,
        __half* __restrict__ q16, __half* __restrict__ kv16,
        int M, int ntiles, int nrowblk) {
    constexpr int NKQ = KD / 32;
    __shared__ __align__(16) _Float16 As[64 * KD];

    int t  = threadIdx.x;
    int wv = t >> 6;
    int L  = t & 63;
    int rL = L & 15;
    int kL = (L >> 4) * 8;
    int colbase = blockIdx.y * 128 + wv * 32;

    // ---- B into registers, once ----
    f16x8 Breg[2][NKQ];
#pragma unroll
    for (int nt = 0; nt < 2; ++nt)
#pragma unroll
        for (int kq = 0; kq < NKQ; ++kq)
            Breg[nt][kq] = *(const f16x8*)(
                BT + (size_t)(colbase + nt * 16 + rL) * KD + kq * 32 + kL);

    float bb[2] = { bias[colbase + rL], bias[colbase + 16 + rL] };

    int r_  = t >> 2;      // stage row 0..63
    int sub = t & 3;

    for (int rt = blockIdx.x; rt < ntiles; rt += nrowblk) {
        int row0 = rt * 64;

        // ---- stage A tile: fp32 -> fp16, swizzled ----
        {
            int gr = row0 + r_;
            const float* Ap = A + (size_t)gr * KD;
            bool val = gr < M;
#pragma unroll
            for (int i = 0; i < NKQ; ++i) {
                int k0 = (sub + 4 * i) * 8;
                float4 x0 = make_float4(0.f, 0.f, 0.f, 0.f), x1 = x0;
                if (val) {
                    x0 = *(const float4*)(Ap + k0);
                    x1 = *(const float4*)(Ap + k0 + 4);
                }
                f16x8 hv;
                hv[0] = (_Float16)x0.x; hv[1] = (_Float16)x0.y;
                hv[2] = (_Float16)x0.z; hv[3] = (_Float16)x0.w;
                hv[4] = (_Float16)x1.x; hv[5] = (_Float16)x1.y;
                hv[6] = (_Float16)x1.z; hv[7] = (_Float16)x1.w;
                int ks = k0 ^ (8 * (r_ & 7));
                *(f16x8*)&As[r_ * KD + ks] = hv;
            }
        }
        __syncthreads();

        // ---- K-loop: LDS + regs only ----
        f32x4 acc[4][2] = {};
#pragma unroll
        for (int kq = 0; kq < NKQ; ++kq) {
            int ksk = kq * 32 + kL;
            f16x8 af[4];
#pragma unroll
            for (int mt = 0; mt < 4; ++mt) {
                int r = mt * 16 + rL;
                int k = ksk ^ (8 * (r & 7));
                af[mt] = *(const f16x8*)&As[r * KD + k];
            }
#pragma unroll
            for (int mt = 0; mt < 4; ++mt) {
                acc[mt][0] = __builtin_amdgcn_mfma_f32_16x16x32_f16(
                    af[mt], Breg[0][kq], acc[mt][0], 0, 0, 0);
                acc[mt][1] = __builtin_amdgcn_mfma_f32_16x16x32_f16(
                    af[mt], Breg[1][kq], acc[mt][1], 0, 0, 0);
            }
        }
        __syncthreads();   // all LDS reads done before next tile's stage

        // ---- epilogue ----
        int cr0 = (L >> 4) * 4;
#pragma unroll
        for (int nt = 0; nt < 2; ++nt) {
            int col = colbase + nt * 16 + rL;
#pragma unroll
            for (int mt = 0; mt < 4; ++mt)
#pragma unroll
                for (int j = 0; j < 4; ++j) {
                    int R = row0 + mt * 16 + cr0 + j;
                    if (R < M) {
                        float v = acc[mt][nt][j] + bb[nt];
                        if (QKV_EPI) {
                            if (col < 128) q16[(size_t)R * 128 + col] = __float2half(v);
                            else kv16[(size_t)R * 256 + (col - 128)] = __float2half(v);
                        } else {
                            Cq[(size_t)R * 128 + col] = v;
                        }
                    }
                }
        }
    }
}

// ---------------------------------------------------------------------------
// Counting sort of edges by dst: histogram -> 2-level exclusive scan -> scatter
// ---------------------------------------------------------------------------
__global__ void k_hist(const int* __restrict__ dst, int* __restrict__ deg, int e) {
    int i = blockIdx.x * 256 + threadIdx.x;
    if (i < e) atomicAdd(&deg[dst[i]], 1);
}

__global__ void k_scan1(const int* __restrict__ in, int* __restrict__ out,
                        int* __restrict__ bsums, int n) {
    __shared__ int sc[256];
    int t = threadIdx.x;
    int base = blockIdx.x * 1024 + t * 4;
    int v[4];
#pragma unroll
    for (int i = 0; i < 4; ++i) v[i] = (base + i < n) ? in[base + i] : 0;
    int tsum = v[0] + v[1] + v[2] + v[3];
    sc[t] = tsum;
    __syncthreads();
    for (int off = 1; off < 256; off <<= 1) {
        int x = 0;
        if (t >= off) x = sc[t - off];
        __syncthreads();
        sc[t] += x;
        __syncthreads();
    }
    int incl = sc[t];
    int e = incl - tsum;
#pragma unroll
    for (int i = 0; i < 4; ++i) {
        if (base + i < n) out[base + i] = e;
        e += v[i];
    }
    if (t == 255) bsums[blockIdx.x] = incl;
}

__global__ void k_scan2(int* __restrict__ bsums, int nb) {
    __shared__ int sc[256];
    int t = threadIdx.x;
    int v = (t < nb) ? bsums[t] : 0;
    sc[t] = v;
    __syncthreads();
    for (int off = 1; off < 256; off <<= 1) {
        int x = 0;
        if (t >= off) x = sc[t - off];
        __syncthreads();
        sc[t] += x;
        __syncthreads();
    }
    if (t < nb) bsums[t] = sc[t] - v;
}

__global__ void k_scan3(int* __restrict__ out, const int* __restrict__ bsums, int n) {
    int i = blockIdx.x * 256 + threadIdx.x;
    if (i < n) out[i] += bsums[blockIdx.x >> 2];
}

__global__ void k_scatter(const int* __restrict__ src, const int* __restrict__ dst,
                          const int* __restrict__ row_start, int* __restrict__ cursor,
                          int* __restrict__ sorted_src, int e) {
    int i = blockIdx.x * 256 + threadIdx.x;
    if (i < e) {
        int d  = dst[i];
        int p  = atomicAdd(&cursor[d], 1);
        sorted_src[row_start[d] + p] = src[i];
    }
}

// ---------------------------------------------------------------------------
// Fused SDDMM + edge-softmax + SPMM. One wave per dst node.
// v4: no-max softmax (exp(s)/sum — mathematically identical ratio, |s|<~20
// is safe in fp32), fdot2 for the 2-dim score partial (q fp16), split
// even/odd accumulators to halve dependent-FMA chain depth.
// ---------------------------------------------------------------------------
__global__ __launch_bounds__(256) void edge_agg(
        const __half* __restrict__ q16, const __half* __restrict__ kv16,
        const int* __restrict__ row_start, const int* __restrict__ deg,
        const int* __restrict__ sorted_src,
        float* __restrict__ agg, int nnodes) {
    int wid  = threadIdx.x >> 6;
    int lane = threadIdx.x & 63;
    int node = blockIdx.x * 4 + wid;
    if (node >= nnodes) return;

    unsigned int qbits = *(const unsigned int*)(q16 + (size_t)node * 128 + 2 * lane);
    f16x2 qh = *(const f16x2*)&qbits;

    float z0 = 0.f, z1 = 0.f;
    float a0 = 0.f, a1 = 0.f;   // acc dim0 even/odd
    float b0 = 0.f, b1 = 0.f;   // acc dim1 even/odd
    int rs = row_start[node];
    int dg = deg[node];

    for (int base = 0; base < dg; base += 16) {
        int rem = dg - base;   // >= 1
        int my_src = (lane < 16 && base + lane < dg) ? sorted_src[rs + base + lane] : 0;

        unsigned int kbits[16], vbits[16];
#pragma unroll
        for (int j = 0; j < 16; ++j) {
            int sn = __builtin_amdgcn_readlane(my_src, j);   // uniform row idx
            const __half* rowp = kv16 + (size_t)sn * 256 + 2 * lane;
            kbits[j] = *(const unsigned int*)rowp;           // k half2
            vbits[j] = *(const unsigned int*)(rowp + 128);   // v half2
        }

#pragma unroll
        for (int j = 0; j < 16; ++j) {
            f16x2 kh = *(const f16x2*)&kbits[j];
            float pp = __builtin_amdgcn_fdot2(kh, qh, 0.f, false);
            pp += __shfl_xor(pp, 1);
            pp += __shfl_xor(pp, 2);
            pp += __shfl_xor(pp, 4);     // all 8 lanes of head group hold dot
            float s = (j < rem) ? pp * 0.25f : -INFINITY;    // 1/sqrt(16)
            float w = __expf(s);          // tail: exp(-inf)=0
            float2 vf = __half22float2(*(const __half2*)&vbits[j]);
            if (j & 1) {
                z1 += w;
                a1 = fmaf(w, vf.x, a1);
                b1 = fmaf(w, vf.y, b1);
            } else {
                z0 += w;
                a0 = fmaf(w, vf.x, a0);
                b0 = fmaf(w, vf.y, b0);
            }
        }
    }
    float z = z0 + z1;
    float inv = (z > 0.f) ? 1.f / z : 0.f;   // deg-0 node -> zeros
    *(float2*)(agg + (size_t)node * OUT_F + 2 * lane) =
        make_float2((a0 + a1) * inv, (b0 + b1) * inv);
}

// ---------------------------------------------------------------------------
extern "C" void kernel_launch(void* const* d_in, const int* in_sizes, int n_in,
                              void* d_out, int out_size, void* d_ws, size_t ws_size,
                              hipStream_t stream) {
    const float* h     = (const float*)d_in[0];
    const float* Wq    = (const float*)d_in[1];
    const float* bq    = (const float*)d_in[2];
    const float* Wk    = (const float*)d_in[3];
    const float* bk    = (const float*)d_in[4];
    const float* Wv    = (const float*)d_in[5];
    const float* bv    = (const float*)d_in[6];
    const float* Wmsg  = (const float*)d_in[7];
    const float* bmsg  = (const float*)d_in[8];
    const float* Wattn = (const float*)d_in[9];
    const float* battn = (const float*)d_in[10];
    const float* Wa    = (const float*)d_in[11];
    const float* ba    = (const float*)d_in[12];
    const int*   src   = (const int*)d_in[13];
    const int*   dst   = (const int*)d_in[14];
    float* out = (float*)d_out;

    int nn = in_sizes[0] / IN_F;   // 100000
    int ne = in_sizes[13];         // 1600000

    char* p = (char*)d_ws;
    auto carve = [&](size_t bytes) {
        char* r = p;
        p += (bytes + 255) & ~(size_t)255;
        return r;
    };
    _Float16* WT_all = (_Float16*)carve((size_t)QKV_F * IN_F * 2);
    _Float16* WaT    = (_Float16*)carve((size_t)OUT_F * OUT_F * 2);
    float*    b_all  = (float*)carve((size_t)QKV_F * 4);
    __half*   q16    = (__half*)carve((size_t)nn * 128 * 2);
    __half*   kv16   = (__half*)carve((size_t)nn * 256 * 2);
    float*    agg    = (float*)carve((size_t)nn * OUT_F * 4);
    int* deg     = (int*)carve((size_t)nn * 4);
    int* rowst   = (int*)carve((size_t)nn * 4);
    int* cursor  = (int*)carve((size_t)nn * 4);
    int* bsums   = (int*)carve(4096);
    int* ssrc    = (int*)carve((size_t)ne * 4);

    hipMemsetAsync(deg, 0, (size_t)nn * 4, stream);
    hipMemsetAsync(cursor, 0, (size_t)nn * 4, stream);

    prep_W<<<IN_F, QKV_F, 0, stream>>>(Wq, Wk, Wattn, Wv, Wmsg, WT_all);
    prep_b<<<1, QKV_F, 0, stream>>>(bq, bk, battn, bv, bmsg, Wattn, Wmsg, b_all);
    t_cast16<<<OUT_F, OUT_F, 0, stream>>>(Wa, WaT, OUT_F, OUT_F);

    int ntiles = (nn + 63) / 64;             // 64-row tiles

    // q (fp16) + k|v (fp16) = h @ W_all + b_all   [fp16 MFMA, B-stationary]
    {
        int nrb = ntiles < 176 ? ntiles : 176;
        mfma_gemm<IN_F, true><<<dim3(nrb, QKV_F / 128), 256, 0, stream>>>(
            h, WT_all, b_all, nullptr, q16, kv16, nn, ntiles, nrb);
    }

    // counting sort edges by dst
    k_hist<<<(ne + 255) / 256, 256, 0, stream>>>(dst, deg, ne);
    int nb = (nn + 1023) / 1024;
    k_scan1<<<nb, 256, 0, stream>>>(deg, rowst, bsums, nn);
    k_scan2<<<1, 256, 0, stream>>>(bsums, nb);
    k_scan3<<<(nn + 255) / 256, 256, 0, stream>>>(rowst, bsums, nn);
    k_scatter<<<(ne + 255) / 256, 256, 0, stream>>>(src, dst, rowst, cursor, ssrc, ne);

    // fused SDDMM + softmax + SPMM
    edge_agg<<<(nn + 3) / 4, 256, 0, stream>>>(q16, kv16, rowst, deg, ssrc, agg, nn);

    // out = agg @ Wa + ba   [fp16 MFMA, B-stationary]
    {
        int nrb = ntiles < 512 ? ntiles : 512;
        mfma_gemm<OUT_F, false><<<dim3(nrb, 1), 256, 0, stream>>>(
            agg, WaT, ba, out, nullptr, nullptr, nn, ntiles, nrb);
    }
}